// Round 6
// baseline (273.125 us; speedup 1.0000x reference)
//
#include <hip/hip_runtime.h>

// GAT_gate: B=16, N=1024, D=128. FP32 I/O; bf16 MFMA internally, fp32 accum.
//
// Fast path (ws >= 56MB):
//  K0:    WwB = bf16(Ww); W2T = bf16(A^T Ww); wbA = Wb@A (fp32)
//  K1:    h = x@Ww^T+Wb ; u = x@W2T^T+wbA -> h,u bf16; hT bf16 [b][d][n]
//  K2s:   grid 2048: block = 16 rows i x 512 cols j. Reads adj directly
//         (ballot -> 1KB LDS bitmask). A-frags hoisted; dbuf B-frags, 2 MFMA
//         chains. att = mask?exp(e):0 -> bf16 (32MB); partial colsums.
//  K2b:   rl0[j] = 1 / sum_iblk colpart
//  K3g:   pure GEMM h' = relu((att*rl0[j]) @ h) vs hT + LSTM-gate epilogue.
// Fallback (ws < 56MB): round-4 kernels (kmask + k2_stats + k3_fused).

#define B_ 16
#define N_ 1024
#define D_ 128

typedef __attribute__((ext_vector_type(8))) short bf16x8;
typedef __attribute__((ext_vector_type(4))) float f32x4;

__device__ __forceinline__ float b2f(unsigned short u) {
    union { unsigned int i; float f; } v; v.i = ((unsigned int)u) << 16; return v.f;
}
__device__ __forceinline__ unsigned short f2b(float f) {
    union { float f; unsigned int i; } v; v.f = f;
    unsigned int x = v.i;
    return (unsigned short)((x + 0x7fffu + ((x >> 16) & 1u)) >> 16);
}
__device__ __forceinline__ float clamp60(float v) {
    return fminf(fmaxf(v, -60.f), 60.f);
}
__device__ __forceinline__ bf16x8 load8f(const float* p) {
    float4 a = *reinterpret_cast<const float4*>(p);
    float4 b = *reinterpret_cast<const float4*>(p + 4);
    bf16x8 v;
    v[0] = (short)f2b(a.x); v[1] = (short)f2b(a.y);
    v[2] = (short)f2b(a.z); v[3] = (short)f2b(a.w);
    v[4] = (short)f2b(b.x); v[5] = (short)f2b(b.y);
    v[6] = (short)f2b(b.z); v[7] = (short)f2b(b.w);
    return v;
}

// ---------------- K0: fold weights ----------------
__global__ __launch_bounds__(256) void k0_w2t(
    const float* __restrict__ Ww, const float* __restrict__ Wb,
    const float* __restrict__ A, unsigned short* __restrict__ WwB,
    unsigned short* __restrict__ W2T, float* __restrict__ wbA) {
    int t = blockIdx.x * 256 + threadIdx.x;
    int l = t >> 7, f = t & 127;
    float acc = 0.f;
    for (int d = 0; d < 128; ++d)
        acc += A[d * 128 + l] * Ww[d * 128 + f];
    W2T[l * 128 + f] = f2b(acc);
    WwB[t] = f2b(Ww[t]);
    if (blockIdx.x == 0 && threadIdx.x < 128) {
        float s = 0.f;
        for (int d = 0; d < 128; ++d) s += Wb[d] * A[d * 128 + threadIdx.x];
        wbA[threadIdx.x] = s;
    }
}

// ---------------- K1: h, u, hT ----------------
__global__ __launch_bounds__(256) void k1_hu(
    const float* __restrict__ x, const unsigned short* __restrict__ WwB,
    const float* __restrict__ Wb, const unsigned short* __restrict__ W2T,
    const float* __restrict__ wbA,
    unsigned short* __restrict__ h, unsigned short* __restrict__ u,
    unsigned short* __restrict__ hT) {
    __shared__ unsigned short lds[16][128];
    int w = threadIdx.x >> 6, lane = threadIdx.x & 63;
    int c = lane & 15, q = lane >> 4;
    int rowbase = blockIdx.x * 16;
    int b = rowbase >> 10;
    int n0 = rowbase & 1023;

    bf16x8 xa[4];
    const float* xrow = x + (size_t)(rowbase + c) * 128;
#pragma unroll
    for (int ks = 0; ks < 4; ++ks)
        xa[ks] = load8f(xrow + ks * 32 + q * 8);

#pragma unroll
    for (int tt = 0; tt < 2; ++tt) {
        int t = w * 2 + tt;
        f32x4 acch = {0.f, 0.f, 0.f, 0.f};
        f32x4 accu = {0.f, 0.f, 0.f, 0.f};
        const unsigned short* wwrow = WwB + (t * 16 + c) * 128;
        const unsigned short* w2row = W2T + (t * 16 + c) * 128;
#pragma unroll
        for (int ks = 0; ks < 4; ++ks) {
            bf16x8 bw = *reinterpret_cast<const bf16x8*>(wwrow + ks * 32 + q * 8);
            bf16x8 b2 = *reinterpret_cast<const bf16x8*>(w2row + ks * 32 + q * 8);
            acch = __builtin_amdgcn_mfma_f32_16x16x32_bf16(xa[ks], bw, acch, 0, 0, 0);
            accu = __builtin_amdgcn_mfma_f32_16x16x32_bf16(xa[ks], b2, accu, 0, 0, 0);
        }
        float wb = Wb[t * 16 + c];
        float ub = wbA[t * 16 + c];
#pragma unroll
        for (int r = 0; r < 4; ++r) {
            int row = rowbase + q * 4 + r;
            unsigned short hv = f2b(acch[r] + wb);
            unsigned short uv = f2b(accu[r] + ub);
            h[(size_t)row * 128 + t * 16 + c] = hv;
            u[(size_t)row * 128 + t * 16 + c] = uv;
            lds[q * 4 + r][t * 16 + c] = hv;
        }
    }
    __syncthreads();
    int tid = threadIdx.x;
    if (tid < 128) {
        int d = tid;
        unsigned int p[8];
#pragma unroll
        for (int k = 0; k < 8; ++k) {
            unsigned int v0 = lds[2 * k][d], v1 = lds[2 * k + 1][d];
            p[k] = v0 | (v1 << 16);
        }
        size_t basehT = ((size_t)(b * 128 + d)) * 1024 + n0;
        uint4* dst = reinterpret_cast<uint4*>(hT + basehT);
        dst[0] = make_uint4(p[0], p[1], p[2], p[3]);
        dst[1] = make_uint4(p[4], p[5], p[6], p[7]);
    }
}

// ========== FAST PATH ==========

// K2s: grid 2048: block = 16 rows x 512 cols. adj read in-kernel via ballot.
__global__ __launch_bounds__(256) void k2_scores(
    const unsigned short* __restrict__ h, const unsigned short* __restrict__ u,
    const float* __restrict__ adj,
    unsigned short* __restrict__ att, float* __restrict__ colpart) {
    __shared__ unsigned long long lmask[16][8];   // [row][64-col word] for j-half
    int w = threadIdx.x >> 6, lane = threadIdx.x & 63;
    int c = lane & 15, q = lane >> 4;
    int b = blockIdx.x >> 7;
    int iblk = (blockIdx.x >> 1) & 63;
    int jh = blockIdx.x & 1;
    int i0 = iblk * 16;
    int jbase = jh * 512;
    const unsigned short* hb = h + (size_t)b * N_ * D_;
    const unsigned short* ub = u + (size_t)b * N_ * D_;

    // ballot phase: wave w handles rows 4w..4w+3, 8 words of 64 cols each
    {
        const float* adjb = adj + ((size_t)(b * 1024 + i0 + w * 4)) * 1024 + jbase;
#pragma unroll
        for (int r = 0; r < 4; ++r) {
#pragma unroll
            for (int g = 0; g < 8; ++g) {
                unsigned long long m = __ballot(adjb[(size_t)r * 1024 + g * 64 + lane] > 0.f);
                if (lane == 0) lmask[w * 4 + r][g] = m;
            }
        }
    }

    bf16x8 Au[4], Ah[4];
#pragma unroll
    for (int ks = 0; ks < 4; ++ks) {
        Au[ks] = *reinterpret_cast<const bf16x8*>(ub + (i0 + c) * 128 + ks * 32 + q * 8);
        Ah[ks] = *reinterpret_cast<const bf16x8*>(hb + (i0 + c) * 128 + ks * 32 + q * 8);
    }
    __syncthreads();

    unsigned short* attrow = att + ((size_t)(b * 1024 + i0)) * 1024;
    float* cprow = colpart + ((size_t)(b * 64 + iblk)) * 1024;

    // wave w: local tiles w*8 .. w*8+7 (16 cols each) within this j-half
    int jt0 = w * 8;
    bf16x8 Bh[2][4], Bu[2][4];
#pragma unroll
    for (int ks = 0; ks < 4; ++ks) {
        int jg = jbase + jt0 * 16;
        Bh[0][ks] = *reinterpret_cast<const bf16x8*>(hb + (jg + c) * 128 + ks * 32 + q * 8);
        Bu[0][ks] = *reinterpret_cast<const bf16x8*>(ub + (jg + c) * 128 + ks * 32 + q * 8);
    }
#pragma unroll
    for (int t = 0; t < 8; ++t) {
        int jtl = jt0 + t;                      // local tile 0..31
        int j0g = jbase + jtl * 16;             // global col base
        int cur = t & 1, nxt = cur ^ 1;
        if (t < 7) {
            int jn = jbase + (jtl + 1) * 16;
#pragma unroll
            for (int ks = 0; ks < 4; ++ks) {
                Bh[nxt][ks] = *reinterpret_cast<const bf16x8*>(hb + (jn + c) * 128 + ks * 32 + q * 8);
                Bu[nxt][ks] = *reinterpret_cast<const bf16x8*>(ub + (jn + c) * 128 + ks * 32 + q * 8);
            }
        }
        f32x4 a1 = {0.f, 0.f, 0.f, 0.f};
        f32x4 a2 = {0.f, 0.f, 0.f, 0.f};
#pragma unroll
        for (int ks = 0; ks < 4; ++ks) {
            a1 = __builtin_amdgcn_mfma_f32_16x16x32_bf16(Au[ks], Bh[cur][ks], a1, 0, 0, 0);
            a2 = __builtin_amdgcn_mfma_f32_16x16x32_bf16(Ah[ks], Bu[cur][ks], a2, 0, 0, 0);
        }
        int wd = jtl >> 2, sh = (jtl & 3) * 16;
        float colp = 0.f;
#pragma unroll
        for (int r = 0; r < 4; ++r) {
            float e = a1[r] + a2[r];            // e[i0+q*4+r][j0g+c]
            bool m = (lmask[q * 4 + r][wd] >> (sh + c)) & 1ull;
            float ex = m ? __expf(clamp60(e)) : 0.f;
            colp += m ? ex : 1.0f;
            attrow[(size_t)(q * 4 + r) * 1024 + j0g + c] = f2b(ex);
        }
        colp += __shfl_xor(colp, 16, 64);
        colp += __shfl_xor(colp, 32, 64);
        if (q == 0) cprow[j0g + c] = colp;
    }
}

// K2b: rl0 = 1/sum(colpart)
__global__ __launch_bounds__(256) void k2b_recip(
    const float* __restrict__ colpart, float* __restrict__ rl0) {
    int g = blockIdx.x * 256 + threadIdx.x;   // 0..16383
    int b = g >> 10, j = g & 1023;
    float s = 0.f;
    const float* p = colpart + (size_t)b * 64 * 1024 + j;
    for (int ib = 0; ib < 64; ++ib) s += p[(size_t)ib * 1024];
    rl0[g] = 1.0f / s;
}

// K3g: pure GEMM h' = relu((att*rl0) @ h) + gates. att is bf16.
__global__ __launch_bounds__(256) void k3_gemm(
    const unsigned short* __restrict__ att, const float* __restrict__ rl0,
    const unsigned short* __restrict__ hT, const float* __restrict__ x,
    const float* __restrict__ wi_u, const float* __restrict__ wi_x,
    const float* __restrict__ wf_u, const float* __restrict__ wf_x,
    const float* __restrict__ wo_u, const float* __restrict__ wo_x,
    float* __restrict__ out) {
    __shared__ float red[4][16][129];
    int w = threadIdx.x >> 6, lane = threadIdx.x & 63;
    int c = lane & 15, q = lane >> 4;
    int b = blockIdx.x >> 6;
    int i0 = (blockIdx.x & 63) * 16;
    const unsigned short* attrow = att + ((size_t)(b * 1024 + i0 + c)) * 1024;
    const unsigned short* hTb = hT + (size_t)b * 128 * 1024;
    const float* rl0b = rl0 + b * 1024;

    f32x4 hp[8];
#pragma unroll
    for (int t = 0; t < 8; ++t) hp[t] = (f32x4){0.f, 0.f, 0.f, 0.f};

#pragma unroll
    for (int tt = 0; tt < 8; ++tt) {
        int jp = w * 8 + tt;
        int jb = jp * 32 + q * 8;
        bf16x8 eraw = *reinterpret_cast<const bf16x8*>(attrow + jb);
        float4 r0 = *reinterpret_cast<const float4*>(rl0b + jb);
        float4 r1 = *reinterpret_cast<const float4*>(rl0b + jb + 4);
        bf16x8 a;
        a[0] = (short)f2b(b2f((unsigned short)eraw[0]) * r0.x);
        a[1] = (short)f2b(b2f((unsigned short)eraw[1]) * r0.y);
        a[2] = (short)f2b(b2f((unsigned short)eraw[2]) * r0.z);
        a[3] = (short)f2b(b2f((unsigned short)eraw[3]) * r0.w);
        a[4] = (short)f2b(b2f((unsigned short)eraw[4]) * r1.x);
        a[5] = (short)f2b(b2f((unsigned short)eraw[5]) * r1.y);
        a[6] = (short)f2b(b2f((unsigned short)eraw[6]) * r1.z);
        a[7] = (short)f2b(b2f((unsigned short)eraw[7]) * r1.w);
#pragma unroll
        for (int t = 0; t < 8; ++t) {
            bf16x8 bt = *reinterpret_cast<const bf16x8*>(
                hTb + (size_t)(t * 16 + c) * 1024 + jp * 32 + q * 8);
            hp[t] = __builtin_amdgcn_mfma_f32_16x16x32_bf16(a, bt, hp[t], 0, 0, 0);
        }
    }

#pragma unroll
    for (int t = 0; t < 8; ++t)
#pragma unroll
        for (int r = 0; r < 4; ++r)
            red[w][q * 4 + r][t * 16 + c] = hp[t][r];
    __syncthreads();
    if (w != 0) return;

#pragma unroll
    for (int t = 0; t < 8; ++t)
#pragma unroll
        for (int r = 0; r < 4; ++r)
            hp[t][r] = red[0][q * 4 + r][t * 16 + c] + red[1][q * 4 + r][t * 16 + c]
                     + red[2][q * 4 + r][t * 16 + c] + red[3][q * 4 + r][t * 16 + c];

    float xv[8][4];
#pragma unroll
    for (int t = 0; t < 8; ++t)
#pragma unroll
        for (int r = 0; r < 4; ++r) {
            hp[t][r] = fmaxf(hp[t][r], 0.f);
            xv[t][r] = x[(size_t)(b * 1024 + i0 + q * 4 + r) * 128 + t * 16 + c];
        }
    float wiu[8], wix[8], wfu[8], wfx[8], wou[8], wox[8];
#pragma unroll
    for (int t = 0; t < 8; ++t) {
        wiu[t] = wi_u[t * 16 + c]; wix[t] = wi_x[t * 16 + c];
        wfu[t] = wf_u[t * 16 + c]; wfx[t] = wf_x[t * 16 + c];
        wou[t] = wo_u[t * 16 + c]; wox[t] = wo_x[t * 16 + c];
    }
#pragma unroll
    for (int r = 0; r < 4; ++r) {
        float zi = 0.f, zf = 0.f, zo = 0.f;
#pragma unroll
        for (int t = 0; t < 8; ++t) {
            zi += hp[t][r] * wiu[t] + xv[t][r] * wix[t];
            zf += hp[t][r] * wfu[t] + xv[t][r] * wfx[t];
            zo += hp[t][r] * wou[t] + xv[t][r] * wox[t];
        }
        zi += __shfl_xor(zi, 1, 64); zi += __shfl_xor(zi, 2, 64);
        zi += __shfl_xor(zi, 4, 64); zi += __shfl_xor(zi, 8, 64);
        zf += __shfl_xor(zf, 1, 64); zf += __shfl_xor(zf, 2, 64);
        zf += __shfl_xor(zf, 4, 64); zf += __shfl_xor(zf, 8, 64);
        zo += __shfl_xor(zo, 1, 64); zo += __shfl_xor(zo, 2, 64);
        zo += __shfl_xor(zo, 4, 64); zo += __shfl_xor(zo, 8, 64);
        float ic = 1.f / (1.f + __expf(-zi));
        float fc = 1.f / (1.f + __expf(-zf));
        float oc = 1.f / (1.f + __expf(-zo));
#pragma unroll
        for (int t = 0; t < 8; ++t) {
            float zz = ic * hp[t][r] + fc * xv[t][r];
            float th = 1.f - 2.f / (__expf(2.f * zz) + 1.f);
            out[(size_t)(b * 1024 + i0 + q * 4 + r) * 128 + t * 16 + c] = oc * th;
        }
    }
}

// ========== FALLBACK PATH (round-4, proven) ==========
__global__ __launch_bounds__(256) void kmask(
    const float* __restrict__ adj, unsigned long long* __restrict__ maskJ) {
    int w = threadIdx.x >> 6, lane = threadIdx.x & 63;
    size_t base = ((size_t)blockIdx.x * 4 + w) * 256;
    unsigned long long w0 = __ballot(adj[base + 0 * 64 + lane] > 0.f);
    unsigned long long w1 = __ballot(adj[base + 1 * 64 + lane] > 0.f);
    unsigned long long w2 = __ballot(adj[base + 2 * 64 + lane] > 0.f);
    unsigned long long w3 = __ballot(adj[base + 3 * 64 + lane] > 0.f);
    unsigned long long o = lane == 0 ? w0 : lane == 1 ? w1 : lane == 2 ? w2 : w3;
    if (lane < 4) maskJ[(base >> 6) + lane] = o;
}

__global__ __launch_bounds__(256) void k2_stats(
    const unsigned short* __restrict__ h, const unsigned short* __restrict__ u,
    const unsigned long long* __restrict__ maskJ, float* __restrict__ rl0) {
    int w = threadIdx.x >> 6, lane = threadIdx.x & 63;
    int c = lane & 15, q = lane >> 4;
    int b = blockIdx.x >> 6;
    int j0 = (blockIdx.x & 63) * 16;
    const unsigned short* hb = h + (size_t)b * N_ * D_;
    const unsigned short* ub = u + (size_t)b * N_ * D_;

    bf16x8 Bh[4], Bu[4];
#pragma unroll
    for (int ks = 0; ks < 4; ++ks) {
        Bh[ks] = *reinterpret_cast<const bf16x8*>(hb + (j0 + c) * 128 + ks * 32 + q * 8);
        Bu[ks] = *reinterpret_cast<const bf16x8*>(ub + (j0 + c) * 128 + ks * 32 + q * 8);
    }
    float colsum = 0.f;
    const unsigned long long* mrow = maskJ + (size_t)b * 1024 * 16 + (j0 >> 6);
    int jb = j0 & 63;

    for (int it = w; it < 64; it += 4) {
        int i0 = it * 16;
        f32x4 acc = {0.f, 0.f, 0.f, 0.f};
#pragma unroll
        for (int ks = 0; ks < 4; ++ks) {
            bf16x8 au = *reinterpret_cast<const bf16x8*>(ub + (i0 + c) * 128 + ks * 32 + q * 8);
            bf16x8 ah = *reinterpret_cast<const bf16x8*>(hb + (i0 + c) * 128 + ks * 32 + q * 8);
            acc = __builtin_amdgcn_mfma_f32_16x16x32_bf16(au, Bh[ks], acc, 0, 0, 0);
            acc = __builtin_amdgcn_mfma_f32_16x16x32_bf16(ah, Bu[ks], acc, 0, 0, 0);
        }
#pragma unroll
        for (int r = 0; r < 4; ++r) {
            int i = i0 + q * 4 + r;
            unsigned long long mword = mrow[(size_t)i * 16];
            bool m = (mword >> (jb + c)) & 1ull;
            colsum += m ? __expf(clamp60(acc[r])) : 1.0f;
        }
    }
    colsum += __shfl_xor(colsum, 16, 64);
    colsum += __shfl_xor(colsum, 32, 64);
    __shared__ float part[4][16];
    if (lane < 16) part[w][lane] = colsum;
    __syncthreads();
    if (threadIdx.x < 16) {
        float s = part[0][threadIdx.x] + part[1][threadIdx.x]
                + part[2][threadIdx.x] + part[3][threadIdx.x];
        rl0[b * 1024 + j0 + threadIdx.x] = 1.0f / s;
    }
}

__global__ __launch_bounds__(256) void k3_fused(
    const unsigned short* __restrict__ h, const unsigned short* __restrict__ uu,
    const unsigned long long* __restrict__ maskJ, const float* __restrict__ rl0,
    const unsigned short* __restrict__ hT, const float* __restrict__ x,
    const float* __restrict__ wi_u, const float* __restrict__ wi_x,
    const float* __restrict__ wf_u, const float* __restrict__ wf_x,
    const float* __restrict__ wo_u, const float* __restrict__ wo_x,
    float* __restrict__ out) {
    __shared__ float red[4][16][129];
    int w = threadIdx.x >> 6, lane = threadIdx.x & 63;
    int c = lane & 15, q = lane >> 4;
    int b = blockIdx.x >> 6;
    int i0 = (blockIdx.x & 63) * 16;
    const unsigned short* hb = h + (size_t)b * N_ * D_;
    const unsigned short* ub = uu + (size_t)b * N_ * D_;
    const unsigned short* hTb = hT + (size_t)b * 128 * 1024;
    const unsigned long long* mrowI = maskJ + (size_t)(b * 1024 + i0 + c) * 16;
    const float* rl0b = rl0 + b * 1024;

    bf16x8 Bh[4], Bu[4];
#pragma unroll
    for (int ks = 0; ks < 4; ++ks) {
        Bh[ks] = *reinterpret_cast<const bf16x8*>(hb + (i0 + c) * 128 + ks * 32 + q * 8);
        Bu[ks] = *reinterpret_cast<const bf16x8*>(ub + (i0 + c) * 128 + ks * 32 + q * 8);
    }
    f32x4 hp[8];
#pragma unroll
    for (int t = 0; t < 8; ++t) hp[t] = (f32x4){0.f, 0.f, 0.f, 0.f};

    for (int jp = w; jp < 32; jp += 4) {
        int j0 = jp * 32;
        unsigned long long mw64 = mrowI[jp >> 1];
        unsigned int mbits = (unsigned int)(mw64 >> ((jp & 1) * 32));
        unsigned int u00, u01, u10, u11;
#pragma unroll
        for (int s = 0; s < 2; ++s) {
            int js = j0 + s * 16;
            f32x4 acc = {0.f, 0.f, 0.f, 0.f};
#pragma unroll
            for (int ks = 0; ks < 4; ++ks) {
                bf16x8 au = *reinterpret_cast<const bf16x8*>(ub + (js + c) * 128 + ks * 32 + q * 8);
                bf16x8 ah = *reinterpret_cast<const bf16x8*>(hb + (js + c) * 128 + ks * 32 + q * 8);
                acc = __builtin_amdgcn_mfma_f32_16x16x32_bf16(au, Bh[ks], acc, 0, 0, 0);
                acc = __builtin_amdgcn_mfma_f32_16x16x32_bf16(ah, Bu[ks], acc, 0, 0, 0);
            }
            float4 rv = *reinterpret_cast<const float4*>(rl0b + js + q * 4);
            int bb = s * 16 + q * 4;
            float a0 = ((mbits >> (bb + 0)) & 1u) ? __expf(clamp60(acc[0])) * rv.x : 0.f;
            float a1 = ((mbits >> (bb + 1)) & 1u) ? __expf(clamp60(acc[1])) * rv.y : 0.f;
            float a2 = ((mbits >> (bb + 2)) & 1u) ? __expf(clamp60(acc[2])) * rv.z : 0.f;
            float a3 = ((mbits >> (bb + 3)) & 1u) ? __expf(clamp60(acc[3])) * rv.w : 0.f;
            unsigned int p0 = (unsigned int)f2b(a0) | ((unsigned int)f2b(a1) << 16);
            unsigned int p1 = (unsigned int)f2b(a2) | ((unsigned int)f2b(a3) << 16);
            if (s == 0) { u00 = p0; u01 = p1; } else { u10 = p0; u11 = p1; }
        }
        int la = c + 32 * (q & 1);
        int lb = la + 16;
        unsigned int x0 = __shfl((int)u00, la, 64), x1 = __shfl((int)u01, la, 64);
        unsigned int x2 = __shfl((int)u00, lb, 64), x3 = __shfl((int)u01, lb, 64);
        unsigned int y0 = __shfl((int)u10, la, 64), y1 = __shfl((int)u11, la, 64);
        unsigned int y2 = __shfl((int)u10, lb, 64), y3 = __shfl((int)u11, lb, 64);
        bool hiq = (q >> 1) != 0;
        union { unsigned int ui[4]; bf16x8 v; } att;
        att.ui[0] = hiq ? y0 : x0;
        att.ui[1] = hiq ? y1 : x1;
        att.ui[2] = hiq ? y2 : x2;
        att.ui[3] = hiq ? y3 : x3;
#pragma unroll
        for (int t = 0; t < 8; ++t) {
            bf16x8 bt = *reinterpret_cast<const bf16x8*>(
                hTb + (size_t)(t * 16 + c) * 1024 + j0 + q * 8);
            hp[t] = __builtin_amdgcn_mfma_f32_16x16x32_bf16(att.v, bt, hp[t], 0, 0, 0);
        }
    }

#pragma unroll
    for (int t = 0; t < 8; ++t)
#pragma unroll
        for (int r = 0; r < 4; ++r)
            red[w][q * 4 + r][t * 16 + c] = hp[t][r];
    __syncthreads();
    if (w != 0) return;

#pragma unroll
    for (int t = 0; t < 8; ++t)
#pragma unroll
        for (int r = 0; r < 4; ++r)
            hp[t][r] = red[0][q * 4 + r][t * 16 + c] + red[1][q * 4 + r][t * 16 + c]
                     + red[2][q * 4 + r][t * 16 + c] + red[3][q * 4 + r][t * 16 + c];

    float xv[8][4];
#pragma unroll
    for (int t = 0; t < 8; ++t)
#pragma unroll
        for (int r = 0; r < 4; ++r) {
            hp[t][r] = fmaxf(hp[t][r], 0.f);
            xv[t][r] = x[(size_t)(b * 1024 + i0 + q * 4 + r) * 128 + t * 16 + c];
        }
    float wiu[8], wix[8], wfu[8], wfx[8], wou[8], wox[8];
#pragma unroll
    for (int t = 0; t < 8; ++t) {
        wiu[t] = wi_u[t * 16 + c]; wix[t] = wi_x[t * 16 + c];
        wfu[t] = wf_u[t * 16 + c]; wfx[t] = wf_x[t * 16 + c];
        wou[t] = wo_u[t * 16 + c]; wox[t] = wo_x[t * 16 + c];
    }
#pragma unroll
    for (int r = 0; r < 4; ++r) {
        float zi = 0.f, zf = 0.f, zo = 0.f;
#pragma unroll
        for (int t = 0; t < 8; ++t) {
            zi += hp[t][r] * wiu[t] + xv[t][r] * wix[t];
            zf += hp[t][r] * wfu[t] + xv[t][r] * wfx[t];
            zo += hp[t][r] * wou[t] + xv[t][r] * wox[t];
        }
        zi += __shfl_xor(zi, 1, 64); zi += __shfl_xor(zi, 2, 64);
        zi += __shfl_xor(zi, 4, 64); zi += __shfl_xor(zi, 8, 64);
        zf += __shfl_xor(zf, 1, 64); zf += __shfl_xor(zf, 2, 64);
        zf += __shfl_xor(zf, 4, 64); zf += __shfl_xor(zf, 8, 64);
        zo += __shfl_xor(zo, 1, 64); zo += __shfl_xor(zo, 2, 64);
        zo += __shfl_xor(zo, 4, 64); zo += __shfl_xor(zo, 8, 64);
        float ic = 1.f / (1.f + __expf(-zi));
        float fc = 1.f / (1.f + __expf(-zf));
        float oc = 1.f / (1.f + __expf(-zo));
#pragma unroll
        for (int t = 0; t < 8; ++t) {
            float zz = ic * hp[t][r] + fc * xv[t][r];
            float th = 1.f - 2.f / (__expf(2.f * zz) + 1.f);
            out[(size_t)(b * 1024 + i0 + q * 4 + r) * 128 + t * 16 + c] = oc * th;
        }
    }
}

extern "C" void kernel_launch(void* const* d_in, const int* in_sizes, int n_in,
                              void* d_out, int out_size, void* d_ws, size_t ws_size,
                              hipStream_t stream) {
    const float* x    = (const float*)d_in[0];
    const float* adj  = (const float*)d_in[1];
    const float* Ww   = (const float*)d_in[2];
    const float* Wb   = (const float*)d_in[3];
    const float* A    = (const float*)d_in[4];
    const float* wi_u = (const float*)d_in[5];
    const float* wi_x = (const float*)d_in[6];
    const float* wf_u = (const float*)d_in[7];
    const float* wf_x = (const float*)d_in[8];
    const float* wo_u = (const float*)d_in[9];
    const float* wo_x = (const float*)d_in[10];
    float* out = (float*)d_out;
    char* ws = (char*)d_ws;

    if (ws_size >= (56ull << 20)) {
        // fast path layout
        unsigned short* WwB = (unsigned short*)(ws);                      // 32K
        unsigned short* W2T = (unsigned short*)(ws + (32u << 10));        // 32K
        float* wbA          = (float*)(ws + (64u << 10));                 // 512B
        float* rl0          = (float*)(ws + (128u << 10));                // 64K
        float* colpart      = (float*)(ws + (4ull << 20));                // 4M
        unsigned short* h   = (unsigned short*)(ws + (8ull << 20));       // 4M
        unsigned short* u   = (unsigned short*)(ws + (12ull << 20));      // 4M
        unsigned short* hT  = (unsigned short*)(ws + (16ull << 20));      // 4M
        unsigned short* att = (unsigned short*)(ws + (20ull << 20));      // 32M

        k0_w2t<<<64, 256, 0, stream>>>(Ww, Wb, A, WwB, W2T, wbA);
        k1_hu<<<1024, 256, 0, stream>>>(x, WwB, Wb, W2T, wbA, h, u, hT);
        k2_scores<<<2048, 256, 0, stream>>>(h, u, adj, att, colpart);
        k2b_recip<<<64, 256, 0, stream>>>(colpart, rl0);
        k3_gemm<<<1024, 256, 0, stream>>>(att, rl0, hT, x,
                                          wi_u, wi_x, wf_u, wf_x, wo_u, wo_x, out);
    } else {
        // fallback: round-4 layout + kernels
        unsigned short* WwB = (unsigned short*)(ws);
        unsigned short* W2T = (unsigned short*)(ws + (32u << 10));
        float* wbA          = (float*)(ws + (64u << 10));
        float* rl0          = (float*)(ws + (128u << 10));
        unsigned short* h   = (unsigned short*)(ws + (1u << 20));
        unsigned short* u   = (unsigned short*)(ws + (5u << 20));
        unsigned short* hT  = (unsigned short*)(ws + (9u << 20));
        unsigned long long* maskJ = (unsigned long long*)(ws + (13u << 20));

        k0_w2t<<<64, 256, 0, stream>>>(Ww, Wb, A, WwB, W2T, wbA);
        kmask<<<16384, 256, 0, stream>>>(adj, maskJ);
        k1_hu<<<1024, 256, 0, stream>>>(x, WwB, Wb, W2T, wbA, h, u, hT);
        k2_stats<<<1024, 256, 0, stream>>>(h, u, maskJ, rl0);
        k3_fused<<<1024, 256, 0, stream>>>(h, u, maskJ, rl0, hT, x,
                                           wi_u, wi_x, wf_u, wf_x, wo_u, wo_x, out);
    }
}

// Round 7
// 249.862 us; speedup vs baseline: 1.0931x; 1.0931x over previous
//
#include <hip/hip_runtime.h>

// GAT_gate: B=16, N=1024, D=128. FP32 I/O; bf16 MFMA internally, fp32 accum.
//
// Fast path (ws >= 56MB):
//  K0:    WwB = bf16(Ww); W2T = bf16(A^T Ww); wbA = Wb@A (fp32)
//  kmask: adj (64MB fp32) -> 2MB bitmask packed along j
//  K1:    h = x@Ww^T+Wb ; u = x@W2T^T+wbA -> h,u bf16; hT bf16 [b][d][n]
//  K2s:   grid 1024: block = 16 rows i x all j. A-frags hoisted; distance-2
//         issue-after-use B prefetch; 2 indep MFMA chains.
//         att = mask?exp(e):0 -> bf16 (32MB); partial colsums (deterministic).
//  K2b:   rl0[j] = 1 / sum_iblk colpart
//  K3g:   pure GEMM h' = relu((att*rl0[j]) @ h) vs hT + LSTM-gate epilogue.
// Fallback (ws < 56MB): round-4 kernels (kmask + k2_stats + k3_fused).

#define B_ 16
#define N_ 1024
#define D_ 128

typedef __attribute__((ext_vector_type(8))) short bf16x8;
typedef __attribute__((ext_vector_type(4))) float f32x4;

__device__ __forceinline__ float b2f(unsigned short u) {
    union { unsigned int i; float f; } v; v.i = ((unsigned int)u) << 16; return v.f;
}
__device__ __forceinline__ unsigned short f2b(float f) {
    union { float f; unsigned int i; } v; v.f = f;
    unsigned int x = v.i;
    return (unsigned short)((x + 0x7fffu + ((x >> 16) & 1u)) >> 16);
}
__device__ __forceinline__ float clamp60(float v) {
    return fminf(fmaxf(v, -60.f), 60.f);
}
__device__ __forceinline__ bf16x8 load8f(const float* p) {
    float4 a = *reinterpret_cast<const float4*>(p);
    float4 b = *reinterpret_cast<const float4*>(p + 4);
    bf16x8 v;
    v[0] = (short)f2b(a.x); v[1] = (short)f2b(a.y);
    v[2] = (short)f2b(a.z); v[3] = (short)f2b(a.w);
    v[4] = (short)f2b(b.x); v[5] = (short)f2b(b.y);
    v[6] = (short)f2b(b.z); v[7] = (short)f2b(b.w);
    return v;
}

// ---------------- K0: fold weights ----------------
__global__ __launch_bounds__(256) void k0_w2t(
    const float* __restrict__ Ww, const float* __restrict__ Wb,
    const float* __restrict__ A, unsigned short* __restrict__ WwB,
    unsigned short* __restrict__ W2T, float* __restrict__ wbA) {
    int t = blockIdx.x * 256 + threadIdx.x;
    int l = t >> 7, f = t & 127;
    float acc = 0.f;
    for (int d = 0; d < 128; ++d)
        acc += A[d * 128 + l] * Ww[d * 128 + f];
    W2T[l * 128 + f] = f2b(acc);
    WwB[t] = f2b(Ww[t]);
    if (blockIdx.x == 0 && threadIdx.x < 128) {
        float s = 0.f;
        for (int d = 0; d < 128; ++d) s += Wb[d] * A[d * 128 + threadIdx.x];
        wbA[threadIdx.x] = s;
    }
}

// ---------------- kmask: adj -> bitmask ----------------
__global__ __launch_bounds__(256) void kmask(
    const float* __restrict__ adj, unsigned long long* __restrict__ maskJ) {
    int w = threadIdx.x >> 6, lane = threadIdx.x & 63;
    size_t base = ((size_t)blockIdx.x * 4 + w) * 256;
    unsigned long long w0 = __ballot(adj[base + 0 * 64 + lane] > 0.f);
    unsigned long long w1 = __ballot(adj[base + 1 * 64 + lane] > 0.f);
    unsigned long long w2 = __ballot(adj[base + 2 * 64 + lane] > 0.f);
    unsigned long long w3 = __ballot(adj[base + 3 * 64 + lane] > 0.f);
    unsigned long long o = lane == 0 ? w0 : lane == 1 ? w1 : lane == 2 ? w2 : w3;
    if (lane < 4) maskJ[(base >> 6) + lane] = o;
}

// ---------------- K1: h, u, hT ----------------
__global__ __launch_bounds__(256) void k1_hu(
    const float* __restrict__ x, const unsigned short* __restrict__ WwB,
    const float* __restrict__ Wb, const unsigned short* __restrict__ W2T,
    const float* __restrict__ wbA,
    unsigned short* __restrict__ h, unsigned short* __restrict__ u,
    unsigned short* __restrict__ hT) {
    __shared__ unsigned short lds[16][128];
    int w = threadIdx.x >> 6, lane = threadIdx.x & 63;
    int c = lane & 15, q = lane >> 4;
    int rowbase = blockIdx.x * 16;
    int b = rowbase >> 10;
    int n0 = rowbase & 1023;

    bf16x8 xa[4];
    const float* xrow = x + (size_t)(rowbase + c) * 128;
#pragma unroll
    for (int ks = 0; ks < 4; ++ks)
        xa[ks] = load8f(xrow + ks * 32 + q * 8);

#pragma unroll
    for (int tt = 0; tt < 2; ++tt) {
        int t = w * 2 + tt;
        f32x4 acch = {0.f, 0.f, 0.f, 0.f};
        f32x4 accu = {0.f, 0.f, 0.f, 0.f};
        const unsigned short* wwrow = WwB + (t * 16 + c) * 128;
        const unsigned short* w2row = W2T + (t * 16 + c) * 128;
#pragma unroll
        for (int ks = 0; ks < 4; ++ks) {
            bf16x8 bw = *reinterpret_cast<const bf16x8*>(wwrow + ks * 32 + q * 8);
            bf16x8 b2 = *reinterpret_cast<const bf16x8*>(w2row + ks * 32 + q * 8);
            acch = __builtin_amdgcn_mfma_f32_16x16x32_bf16(xa[ks], bw, acch, 0, 0, 0);
            accu = __builtin_amdgcn_mfma_f32_16x16x32_bf16(xa[ks], b2, accu, 0, 0, 0);
        }
        float wb = Wb[t * 16 + c];
        float ub = wbA[t * 16 + c];
#pragma unroll
        for (int r = 0; r < 4; ++r) {
            int row = rowbase + q * 4 + r;
            unsigned short hv = f2b(acch[r] + wb);
            unsigned short uv = f2b(accu[r] + ub);
            h[(size_t)row * 128 + t * 16 + c] = hv;
            u[(size_t)row * 128 + t * 16 + c] = uv;
            lds[q * 4 + r][t * 16 + c] = hv;
        }
    }
    __syncthreads();
    int tid = threadIdx.x;
    if (tid < 128) {
        int d = tid;
        unsigned int p[8];
#pragma unroll
        for (int k = 0; k < 8; ++k) {
            unsigned int v0 = lds[2 * k][d], v1 = lds[2 * k + 1][d];
            p[k] = v0 | (v1 << 16);
        }
        size_t basehT = ((size_t)(b * 128 + d)) * 1024 + n0;
        uint4* dst = reinterpret_cast<uint4*>(hT + basehT);
        dst[0] = make_uint4(p[0], p[1], p[2], p[3]);
        dst[1] = make_uint4(p[4], p[5], p[6], p[7]);
    }
}

// ========== FAST PATH ==========

// K2s: grid 1024: block = 16 rows i, all 1024 j. Distance-2 B prefetch.
__global__ __launch_bounds__(256) void k2_scores(
    const unsigned short* __restrict__ h, const unsigned short* __restrict__ u,
    const unsigned long long* __restrict__ maskJ,
    unsigned short* __restrict__ att, float* __restrict__ colpart) {
    __shared__ unsigned long long lmask[16][16];
    int w = threadIdx.x >> 6, lane = threadIdx.x & 63;
    int c = lane & 15, q = lane >> 4;
    int b = blockIdx.x >> 6;
    int iblk = blockIdx.x & 63;
    int i0 = iblk * 16;
    const unsigned short* hb = h + (size_t)b * N_ * D_;
    const unsigned short* ub = u + (size_t)b * N_ * D_;

    lmask[threadIdx.x >> 4][threadIdx.x & 15] =
        maskJ[(size_t)(b * 1024 + i0 + (threadIdx.x >> 4)) * 16 + (threadIdx.x & 15)];
    __syncthreads();

    bf16x8 Au[4], Ah[4];
#pragma unroll
    for (int ks = 0; ks < 4; ++ks) {
        Au[ks] = *reinterpret_cast<const bf16x8*>(ub + (i0 + c) * 128 + ks * 32 + q * 8);
        Ah[ks] = *reinterpret_cast<const bf16x8*>(hb + (i0 + c) * 128 + ks * 32 + q * 8);
    }
    unsigned short* attrow = att + ((size_t)(b * 1024 + i0)) * 1024;
    float* cprow = colpart + ((size_t)(b * 64 + iblk)) * 1024;

    int jt0 = w * 16;                          // wave w: tiles jt0..jt0+15
    bf16x8 Bh[2][4], Bu[2][4];
    // preload tiles jt0, jt0+1
#pragma unroll
    for (int s = 0; s < 2; ++s) {
        int jg = (jt0 + s) * 16;
#pragma unroll
        for (int ks = 0; ks < 4; ++ks) {
            Bh[s][ks] = *reinterpret_cast<const bf16x8*>(hb + (jg + c) * 128 + ks * 32 + q * 8);
            Bu[s][ks] = *reinterpret_cast<const bf16x8*>(ub + (jg + c) * 128 + ks * 32 + q * 8);
        }
    }
#pragma unroll
    for (int t = 0; t < 16; ++t) {
        int jt = jt0 + t, j0 = jt * 16;
        int slot = t & 1;
        f32x4 a1 = {0.f, 0.f, 0.f, 0.f};
        f32x4 a2 = {0.f, 0.f, 0.f, 0.f};
#pragma unroll
        for (int ks = 0; ks < 4; ++ks) {
            a1 = __builtin_amdgcn_mfma_f32_16x16x32_bf16(Au[ks], Bh[slot][ks], a1, 0, 0, 0);
            a2 = __builtin_amdgcn_mfma_f32_16x16x32_bf16(Ah[ks], Bu[slot][ks], a2, 0, 0, 0);
        }
        // distance-2 prefetch into the slot just consumed
        if (t < 14) {
            int jn = (jt + 2) * 16;
#pragma unroll
            for (int ks = 0; ks < 4; ++ks) {
                Bh[slot][ks] = *reinterpret_cast<const bf16x8*>(hb + (jn + c) * 128 + ks * 32 + q * 8);
                Bu[slot][ks] = *reinterpret_cast<const bf16x8*>(ub + (jn + c) * 128 + ks * 32 + q * 8);
            }
        }
        int wd = jt >> 2, sh = (jt & 3) * 16;
        float colp = 0.f;
#pragma unroll
        for (int r = 0; r < 4; ++r) {
            float e = a1[r] + a2[r];            // e[i0+q*4+r][j0+c]
            bool m = (lmask[q * 4 + r][wd] >> (sh + c)) & 1ull;
            float ex = m ? __expf(clamp60(e)) : 0.f;
            colp += m ? ex : 1.0f;
            attrow[(size_t)(q * 4 + r) * 1024 + j0 + c] = f2b(ex);
        }
        colp += __shfl_xor(colp, 16, 64);
        colp += __shfl_xor(colp, 32, 64);
        if (q == 0) cprow[j0 + c] = colp;
    }
}

// K2b: rl0 = 1/sum(colpart)
__global__ __launch_bounds__(256) void k2b_recip(
    const float* __restrict__ colpart, float* __restrict__ rl0) {
    int g = blockIdx.x * 256 + threadIdx.x;   // 0..16383
    int b = g >> 10, j = g & 1023;
    float s = 0.f;
    const float* p = colpart + (size_t)b * 64 * 1024 + j;
    for (int ib = 0; ib < 64; ++ib) s += p[(size_t)ib * 1024];
    rl0[g] = 1.0f / s;
}

// K3g: pure GEMM h' = relu((att*rl0) @ h) + gates. att is bf16.
__global__ __launch_bounds__(256) void k3_gemm(
    const unsigned short* __restrict__ att, const float* __restrict__ rl0,
    const unsigned short* __restrict__ hT, const float* __restrict__ x,
    const float* __restrict__ wi_u, const float* __restrict__ wi_x,
    const float* __restrict__ wf_u, const float* __restrict__ wf_x,
    const float* __restrict__ wo_u, const float* __restrict__ wo_x,
    float* __restrict__ out) {
    __shared__ float red[4][16][129];
    int w = threadIdx.x >> 6, lane = threadIdx.x & 63;
    int c = lane & 15, q = lane >> 4;
    int b = blockIdx.x >> 6;
    int i0 = (blockIdx.x & 63) * 16;
    const unsigned short* attrow = att + ((size_t)(b * 1024 + i0 + c)) * 1024;
    const unsigned short* hTb = hT + (size_t)b * 128 * 1024;
    const float* rl0b = rl0 + b * 1024;

    f32x4 hp[8];
#pragma unroll
    for (int t = 0; t < 8; ++t) hp[t] = (f32x4){0.f, 0.f, 0.f, 0.f};

#pragma unroll
    for (int tt = 0; tt < 8; ++tt) {
        int jp = w * 8 + tt;
        int jb = jp * 32 + q * 8;
        bf16x8 eraw = *reinterpret_cast<const bf16x8*>(attrow + jb);
        float4 r0 = *reinterpret_cast<const float4*>(rl0b + jb);
        float4 r1 = *reinterpret_cast<const float4*>(rl0b + jb + 4);
        bf16x8 a;
        a[0] = (short)f2b(b2f((unsigned short)eraw[0]) * r0.x);
        a[1] = (short)f2b(b2f((unsigned short)eraw[1]) * r0.y);
        a[2] = (short)f2b(b2f((unsigned short)eraw[2]) * r0.z);
        a[3] = (short)f2b(b2f((unsigned short)eraw[3]) * r0.w);
        a[4] = (short)f2b(b2f((unsigned short)eraw[4]) * r1.x);
        a[5] = (short)f2b(b2f((unsigned short)eraw[5]) * r1.y);
        a[6] = (short)f2b(b2f((unsigned short)eraw[6]) * r1.z);
        a[7] = (short)f2b(b2f((unsigned short)eraw[7]) * r1.w);
#pragma unroll
        for (int t = 0; t < 8; ++t) {
            bf16x8 bt = *reinterpret_cast<const bf16x8*>(
                hTb + (size_t)(t * 16 + c) * 1024 + jp * 32 + q * 8);
            hp[t] = __builtin_amdgcn_mfma_f32_16x16x32_bf16(a, bt, hp[t], 0, 0, 0);
        }
    }

#pragma unroll
    for (int t = 0; t < 8; ++t)
#pragma unroll
        for (int r = 0; r < 4; ++r)
            red[w][q * 4 + r][t * 16 + c] = hp[t][r];
    __syncthreads();
    if (w != 0) return;

#pragma unroll
    for (int t = 0; t < 8; ++t)
#pragma unroll
        for (int r = 0; r < 4; ++r)
            hp[t][r] = red[0][q * 4 + r][t * 16 + c] + red[1][q * 4 + r][t * 16 + c]
                     + red[2][q * 4 + r][t * 16 + c] + red[3][q * 4 + r][t * 16 + c];

    float xv[8][4];
#pragma unroll
    for (int t = 0; t < 8; ++t)
#pragma unroll
        for (int r = 0; r < 4; ++r) {
            hp[t][r] = fmaxf(hp[t][r], 0.f);
            xv[t][r] = x[(size_t)(b * 1024 + i0 + q * 4 + r) * 128 + t * 16 + c];
        }
    float wiu[8], wix[8], wfu[8], wfx[8], wou[8], wox[8];
#pragma unroll
    for (int t = 0; t < 8; ++t) {
        wiu[t] = wi_u[t * 16 + c]; wix[t] = wi_x[t * 16 + c];
        wfu[t] = wf_u[t * 16 + c]; wfx[t] = wf_x[t * 16 + c];
        wou[t] = wo_u[t * 16 + c]; wox[t] = wo_x[t * 16 + c];
    }
#pragma unroll
    for (int r = 0; r < 4; ++r) {
        float zi = 0.f, zf = 0.f, zo = 0.f;
#pragma unroll
        for (int t = 0; t < 8; ++t) {
            zi += hp[t][r] * wiu[t] + xv[t][r] * wix[t];
            zf += hp[t][r] * wfu[t] + xv[t][r] * wfx[t];
            zo += hp[t][r] * wou[t] + xv[t][r] * wox[t];
        }
        zi += __shfl_xor(zi, 1, 64); zi += __shfl_xor(zi, 2, 64);
        zi += __shfl_xor(zi, 4, 64); zi += __shfl_xor(zi, 8, 64);
        zf += __shfl_xor(zf, 1, 64); zf += __shfl_xor(zf, 2, 64);
        zf += __shfl_xor(zf, 4, 64); zf += __shfl_xor(zf, 8, 64);
        zo += __shfl_xor(zo, 1, 64); zo += __shfl_xor(zo, 2, 64);
        zo += __shfl_xor(zo, 4, 64); zo += __shfl_xor(zo, 8, 64);
        float ic = 1.f / (1.f + __expf(-zi));
        float fc = 1.f / (1.f + __expf(-zf));
        float oc = 1.f / (1.f + __expf(-zo));
#pragma unroll
        for (int t = 0; t < 8; ++t) {
            float zz = ic * hp[t][r] + fc * xv[t][r];
            float th = 1.f - 2.f / (__expf(2.f * zz) + 1.f);
            out[(size_t)(b * 1024 + i0 + q * 4 + r) * 128 + t * 16 + c] = oc * th;
        }
    }
}

// ========== FALLBACK PATH (round-4, proven) ==========
__global__ __launch_bounds__(256) void k2_stats(
    const unsigned short* __restrict__ h, const unsigned short* __restrict__ u,
    const unsigned long long* __restrict__ maskJ, float* __restrict__ rl0) {
    int w = threadIdx.x >> 6, lane = threadIdx.x & 63;
    int c = lane & 15, q = lane >> 4;
    int b = blockIdx.x >> 6;
    int j0 = (blockIdx.x & 63) * 16;
    const unsigned short* hb = h + (size_t)b * N_ * D_;
    const unsigned short* ub = u + (size_t)b * N_ * D_;

    bf16x8 Bh[4], Bu[4];
#pragma unroll
    for (int ks = 0; ks < 4; ++ks) {
        Bh[ks] = *reinterpret_cast<const bf16x8*>(hb + (j0 + c) * 128 + ks * 32 + q * 8);
        Bu[ks] = *reinterpret_cast<const bf16x8*>(ub + (j0 + c) * 128 + ks * 32 + q * 8);
    }
    float colsum = 0.f;
    const unsigned long long* mrow = maskJ + (size_t)b * 1024 * 16 + (j0 >> 6);
    int jb = j0 & 63;

    for (int it = w; it < 64; it += 4) {
        int i0 = it * 16;
        f32x4 acc = {0.f, 0.f, 0.f, 0.f};
#pragma unroll
        for (int ks = 0; ks < 4; ++ks) {
            bf16x8 au = *reinterpret_cast<const bf16x8*>(ub + (i0 + c) * 128 + ks * 32 + q * 8);
            bf16x8 ah = *reinterpret_cast<const bf16x8*>(hb + (i0 + c) * 128 + ks * 32 + q * 8);
            acc = __builtin_amdgcn_mfma_f32_16x16x32_bf16(au, Bh[ks], acc, 0, 0, 0);
            acc = __builtin_amdgcn_mfma_f32_16x16x32_bf16(ah, Bu[ks], acc, 0, 0, 0);
        }
#pragma unroll
        for (int r = 0; r < 4; ++r) {
            int i = i0 + q * 4 + r;
            unsigned long long mword = mrow[(size_t)i * 16];
            bool m = (mword >> (jb + c)) & 1ull;
            colsum += m ? __expf(clamp60(acc[r])) : 1.0f;
        }
    }
    colsum += __shfl_xor(colsum, 16, 64);
    colsum += __shfl_xor(colsum, 32, 64);
    __shared__ float part[4][16];
    if (lane < 16) part[w][lane] = colsum;
    __syncthreads();
    if (threadIdx.x < 16) {
        float s = part[0][threadIdx.x] + part[1][threadIdx.x]
                + part[2][threadIdx.x] + part[3][threadIdx.x];
        rl0[b * 1024 + j0 + threadIdx.x] = 1.0f / s;
    }
}

__global__ __launch_bounds__(256) void k3_fused(
    const unsigned short* __restrict__ h, const unsigned short* __restrict__ uu,
    const unsigned long long* __restrict__ maskJ, const float* __restrict__ rl0,
    const unsigned short* __restrict__ hT, const float* __restrict__ x,
    const float* __restrict__ wi_u, const float* __restrict__ wi_x,
    const float* __restrict__ wf_u, const float* __restrict__ wf_x,
    const float* __restrict__ wo_u, const float* __restrict__ wo_x,
    float* __restrict__ out) {
    __shared__ float red[4][16][129];
    int w = threadIdx.x >> 6, lane = threadIdx.x & 63;
    int c = lane & 15, q = lane >> 4;
    int b = blockIdx.x >> 6;
    int i0 = (blockIdx.x & 63) * 16;
    const unsigned short* hb = h + (size_t)b * N_ * D_;
    const unsigned short* ub = uu + (size_t)b * N_ * D_;
    const unsigned short* hTb = hT + (size_t)b * 128 * 1024;
    const unsigned long long* mrowI = maskJ + (size_t)(b * 1024 + i0 + c) * 16;
    const float* rl0b = rl0 + b * 1024;

    bf16x8 Bh[4], Bu[4];
#pragma unroll
    for (int ks = 0; ks < 4; ++ks) {
        Bh[ks] = *reinterpret_cast<const bf16x8*>(hb + (i0 + c) * 128 + ks * 32 + q * 8);
        Bu[ks] = *reinterpret_cast<const bf16x8*>(ub + (i0 + c) * 128 + ks * 32 + q * 8);
    }
    f32x4 hp[8];
#pragma unroll
    for (int t = 0; t < 8; ++t) hp[t] = (f32x4){0.f, 0.f, 0.f, 0.f};

    for (int jp = w; jp < 32; jp += 4) {
        int j0 = jp * 32;
        unsigned long long mw64 = mrowI[jp >> 1];
        unsigned int mbits = (unsigned int)(mw64 >> ((jp & 1) * 32));
        unsigned int u00, u01, u10, u11;
#pragma unroll
        for (int s = 0; s < 2; ++s) {
            int js = j0 + s * 16;
            f32x4 acc = {0.f, 0.f, 0.f, 0.f};
#pragma unroll
            for (int ks = 0; ks < 4; ++ks) {
                bf16x8 au = *reinterpret_cast<const bf16x8*>(ub + (js + c) * 128 + ks * 32 + q * 8);
                bf16x8 ah = *reinterpret_cast<const bf16x8*>(hb + (js + c) * 128 + ks * 32 + q * 8);
                acc = __builtin_amdgcn_mfma_f32_16x16x32_bf16(au, Bh[ks], acc, 0, 0, 0);
                acc = __builtin_amdgcn_mfma_f32_16x16x32_bf16(ah, Bu[ks], acc, 0, 0, 0);
            }
            float4 rv = *reinterpret_cast<const float4*>(rl0b + js + q * 4);
            int bb = s * 16 + q * 4;
            float a0 = ((mbits >> (bb + 0)) & 1u) ? __expf(clamp60(acc[0])) * rv.x : 0.f;
            float a1 = ((mbits >> (bb + 1)) & 1u) ? __expf(clamp60(acc[1])) * rv.y : 0.f;
            float a2 = ((mbits >> (bb + 2)) & 1u) ? __expf(clamp60(acc[2])) * rv.z : 0.f;
            float a3 = ((mbits >> (bb + 3)) & 1u) ? __expf(clamp60(acc[3])) * rv.w : 0.f;
            unsigned int p0 = (unsigned int)f2b(a0) | ((unsigned int)f2b(a1) << 16);
            unsigned int p1 = (unsigned int)f2b(a2) | ((unsigned int)f2b(a3) << 16);
            if (s == 0) { u00 = p0; u01 = p1; } else { u10 = p0; u11 = p1; }
        }
        int la = c + 32 * (q & 1);
        int lb = la + 16;
        unsigned int x0 = __shfl((int)u00, la, 64), x1 = __shfl((int)u01, la, 64);
        unsigned int x2 = __shfl((int)u00, lb, 64), x3 = __shfl((int)u01, lb, 64);
        unsigned int y0 = __shfl((int)u10, la, 64), y1 = __shfl((int)u11, la, 64);
        unsigned int y2 = __shfl((int)u10, lb, 64), y3 = __shfl((int)u11, lb, 64);
        bool hiq = (q >> 1) != 0;
        union { unsigned int ui[4]; bf16x8 v; } att;
        att.ui[0] = hiq ? y0 : x0;
        att.ui[1] = hiq ? y1 : x1;
        att.ui[2] = hiq ? y2 : x2;
        att.ui[3] = hiq ? y3 : x3;
#pragma unroll
        for (int t = 0; t < 8; ++t) {
            bf16x8 bt = *reinterpret_cast<const bf16x8*>(
                hTb + (size_t)(t * 16 + c) * 1024 + j0 + q * 8);
            hp[t] = __builtin_amdgcn_mfma_f32_16x16x32_bf16(att.v, bt, hp[t], 0, 0, 0);
        }
    }

#pragma unroll
    for (int t = 0; t < 8; ++t)
#pragma unroll
        for (int r = 0; r < 4; ++r)
            red[w][q * 4 + r][t * 16 + c] = hp[t][r];
    __syncthreads();
    if (w != 0) return;

#pragma unroll
    for (int t = 0; t < 8; ++t)
#pragma unroll
        for (int r = 0; r < 4; ++r)
            hp[t][r] = red[0][q * 4 + r][t * 16 + c] + red[1][q * 4 + r][t * 16 + c]
                     + red[2][q * 4 + r][t * 16 + c] + red[3][q * 4 + r][t * 16 + c];

    float xv[8][4];
#pragma unroll
    for (int t = 0; t < 8; ++t)
#pragma unroll
        for (int r = 0; r < 4; ++r) {
            hp[t][r] = fmaxf(hp[t][r], 0.f);
            xv[t][r] = x[(size_t)(b * 1024 + i0 + q * 4 + r) * 128 + t * 16 + c];
        }
    float wiu[8], wix[8], wfu[8], wfx[8], wou[8], wox[8];
#pragma unroll
    for (int t = 0; t < 8; ++t) {
        wiu[t] = wi_u[t * 16 + c]; wix[t] = wi_x[t * 16 + c];
        wfu[t] = wf_u[t * 16 + c]; wfx[t] = wf_x[t * 16 + c];
        wou[t] = wo_u[t * 16 + c]; wox[t] = wo_x[t * 16 + c];
    }
#pragma unroll
    for (int r = 0; r < 4; ++r) {
        float zi = 0.f, zf = 0.f, zo = 0.f;
#pragma unroll
        for (int t = 0; t < 8; ++t) {
            zi += hp[t][r] * wiu[t] + xv[t][r] * wix[t];
            zf += hp[t][r] * wfu[t] + xv[t][r] * wfx[t];
            zo += hp[t][r] * wou[t] + xv[t][r] * wox[t];
        }
        zi += __shfl_xor(zi, 1, 64); zi += __shfl_xor(zi, 2, 64);
        zi += __shfl_xor(zi, 4, 64); zi += __shfl_xor(zi, 8, 64);
        zf += __shfl_xor(zf, 1, 64); zf += __shfl_xor(zf, 2, 64);
        zf += __shfl_xor(zf, 4, 64); zf += __shfl_xor(zf, 8, 64);
        zo += __shfl_xor(zo, 1, 64); zo += __shfl_xor(zo, 2, 64);
        zo += __shfl_xor(zo, 4, 64); zo += __shfl_xor(zo, 8, 64);
        float ic = 1.f / (1.f + __expf(-zi));
        float fc = 1.f / (1.f + __expf(-zf));
        float oc = 1.f / (1.f + __expf(-zo));
#pragma unroll
        for (int t = 0; t < 8; ++t) {
            float zz = ic * hp[t][r] + fc * xv[t][r];
            float th = 1.f - 2.f / (__expf(2.f * zz) + 1.f);
            out[(size_t)(b * 1024 + i0 + q * 4 + r) * 128 + t * 16 + c] = oc * th;
        }
    }
}

extern "C" void kernel_launch(void* const* d_in, const int* in_sizes, int n_in,
                              void* d_out, int out_size, void* d_ws, size_t ws_size,
                              hipStream_t stream) {
    const float* x    = (const float*)d_in[0];
    const float* adj  = (const float*)d_in[1];
    const float* Ww   = (const float*)d_in[2];
    const float* Wb   = (const float*)d_in[3];
    const float* A    = (const float*)d_in[4];
    const float* wi_u = (const float*)d_in[5];
    const float* wi_x = (const float*)d_in[6];
    const float* wf_u = (const float*)d_in[7];
    const float* wf_x = (const float*)d_in[8];
    const float* wo_u = (const float*)d_in[9];
    const float* wo_x = (const float*)d_in[10];
    float* out = (float*)d_out;
    char* ws = (char*)d_ws;

    if (ws_size >= (56ull << 20)) {
        // fast path layout
        unsigned short* WwB = (unsigned short*)(ws);                      // 32K
        unsigned short* W2T = (unsigned short*)(ws + (32u << 10));        // 32K
        float* wbA          = (float*)(ws + (64u << 10));                 // 512B
        float* rl0          = (float*)(ws + (128u << 10));                // 64K
        unsigned long long* maskJ = (unsigned long long*)(ws + (256u << 10)); // 2M
        float* colpart      = (float*)(ws + (4ull << 20));                // 4M
        unsigned short* h   = (unsigned short*)(ws + (8ull << 20));       // 4M
        unsigned short* u   = (unsigned short*)(ws + (12ull << 20));      // 4M
        unsigned short* hT  = (unsigned short*)(ws + (16ull << 20));      // 4M
        unsigned short* att = (unsigned short*)(ws + (20ull << 20));      // 32M

        k0_w2t<<<64, 256, 0, stream>>>(Ww, Wb, A, WwB, W2T, wbA);
        kmask<<<16384, 256, 0, stream>>>(adj, maskJ);
        k1_hu<<<1024, 256, 0, stream>>>(x, WwB, Wb, W2T, wbA, h, u, hT);
        k2_scores<<<1024, 256, 0, stream>>>(h, u, maskJ, att, colpart);
        k2b_recip<<<64, 256, 0, stream>>>(colpart, rl0);
        k3_gemm<<<1024, 256, 0, stream>>>(att, rl0, hT, x,
                                          wi_u, wi_x, wf_u, wf_x, wo_u, wo_x, out);
    } else {
        // fallback: round-4 layout + kernels
        unsigned short* WwB = (unsigned short*)(ws);
        unsigned short* W2T = (unsigned short*)(ws + (32u << 10));
        float* wbA          = (float*)(ws + (64u << 10));
        float* rl0          = (float*)(ws + (128u << 10));
        unsigned short* h   = (unsigned short*)(ws + (1u << 20));
        unsigned short* u   = (unsigned short*)(ws + (5u << 20));
        unsigned short* hT  = (unsigned short*)(ws + (9u << 20));
        unsigned long long* maskJ = (unsigned long long*)(ws + (13u << 20));

        k0_w2t<<<64, 256, 0, stream>>>(Ww, Wb, A, WwB, W2T, wbA);
        kmask<<<16384, 256, 0, stream>>>(adj, maskJ);
        k1_hu<<<1024, 256, 0, stream>>>(x, WwB, Wb, W2T, wbA, h, u, hT);
        k2_stats<<<1024, 256, 0, stream>>>(h, u, maskJ, rl0);
        k3_fused<<<1024, 256, 0, stream>>>(h, u, maskJ, rl0, hT, x,
                                           wi_u, wi_x, wf_u, wf_x, wo_u, wo_x, out);
    }
}

// Round 8
// 246.540 us; speedup vs baseline: 1.1078x; 1.0135x over previous
//
#include <hip/hip_runtime.h>

// GAT_gate: B=16, N=1024, D=128. FP32 I/O; bf16 MFMA internally, fp32 accum.
//
// Fast path (ws >= 56MB):
//  K0:    WwB = bf16(Ww); W2T = bf16(A^T Ww); wbA = Wb@A (fp32)
//  K1:    h = x@Ww^T+Wb ; u = x@W2T^T+wbA -> h,u bf16; hT bf16 [b][d][n];
//         + converts its 16 adj rows -> maskJ bitmask (kmask fused in).
//  K2s:   grid 512: block = 32 rows i x all j. 16 A-frags hoisted; per j-tile
//         4 independent MFMA chains (2 row-groups x 2 products) = 16 MFMAs.
//         att = mask?exp(e):0 -> bf16 (32MB); partial colsums (32 rows/blk).
//  K2b:   rl0[j] = 1 / sum_iblk colpart
//  K3g:   pure GEMM h' = relu((att*rl0[j]) @ h) vs hT + LSTM-gate epilogue.
// Fallback (ws < 56MB): round-4 kernels (kmask + k2_stats + k3_fused).

#define B_ 16
#define N_ 1024
#define D_ 128

typedef __attribute__((ext_vector_type(8))) short bf16x8;
typedef __attribute__((ext_vector_type(4))) float f32x4;

__device__ __forceinline__ float b2f(unsigned short u) {
    union { unsigned int i; float f; } v; v.i = ((unsigned int)u) << 16; return v.f;
}
__device__ __forceinline__ unsigned short f2b(float f) {
    union { float f; unsigned int i; } v; v.f = f;
    unsigned int x = v.i;
    return (unsigned short)((x + 0x7fffu + ((x >> 16) & 1u)) >> 16);
}
__device__ __forceinline__ float clamp60(float v) {
    return fminf(fmaxf(v, -60.f), 60.f);
}
__device__ __forceinline__ bf16x8 load8f(const float* p) {
    float4 a = *reinterpret_cast<const float4*>(p);
    float4 b = *reinterpret_cast<const float4*>(p + 4);
    bf16x8 v;
    v[0] = (short)f2b(a.x); v[1] = (short)f2b(a.y);
    v[2] = (short)f2b(a.z); v[3] = (short)f2b(a.w);
    v[4] = (short)f2b(b.x); v[5] = (short)f2b(b.y);
    v[6] = (short)f2b(b.z); v[7] = (short)f2b(b.w);
    return v;
}

// ---------------- K0: fold weights ----------------
__global__ __launch_bounds__(256) void k0_w2t(
    const float* __restrict__ Ww, const float* __restrict__ Wb,
    const float* __restrict__ A, unsigned short* __restrict__ WwB,
    unsigned short* __restrict__ W2T, float* __restrict__ wbA) {
    int t = blockIdx.x * 256 + threadIdx.x;
    int l = t >> 7, f = t & 127;
    float acc = 0.f;
    for (int d = 0; d < 128; ++d)
        acc += A[d * 128 + l] * Ww[d * 128 + f];
    W2T[l * 128 + f] = f2b(acc);
    WwB[t] = f2b(Ww[t]);
    if (blockIdx.x == 0 && threadIdx.x < 128) {
        float s = 0.f;
        for (int d = 0; d < 128; ++d) s += Wb[d] * A[d * 128 + threadIdx.x];
        wbA[threadIdx.x] = s;
    }
}

// ---------------- kmask (fallback only) ----------------
__global__ __launch_bounds__(256) void kmask(
    const float* __restrict__ adj, unsigned long long* __restrict__ maskJ) {
    int w = threadIdx.x >> 6, lane = threadIdx.x & 63;
    size_t base = ((size_t)blockIdx.x * 4 + w) * 256;
    unsigned long long w0 = __ballot(adj[base + 0 * 64 + lane] > 0.f);
    unsigned long long w1 = __ballot(adj[base + 1 * 64 + lane] > 0.f);
    unsigned long long w2 = __ballot(adj[base + 2 * 64 + lane] > 0.f);
    unsigned long long w3 = __ballot(adj[base + 3 * 64 + lane] > 0.f);
    unsigned long long o = lane == 0 ? w0 : lane == 1 ? w1 : lane == 2 ? w2 : w3;
    if (lane < 4) maskJ[(base >> 6) + lane] = o;
}

// ---------------- K1: h, u, hT (+ adj->maskJ fused) ----------------
__global__ __launch_bounds__(256) void k1_hu(
    const float* __restrict__ x, const unsigned short* __restrict__ WwB,
    const float* __restrict__ Wb, const unsigned short* __restrict__ W2T,
    const float* __restrict__ wbA, const float* __restrict__ adj,
    unsigned short* __restrict__ h, unsigned short* __restrict__ u,
    unsigned short* __restrict__ hT, unsigned long long* __restrict__ maskJ) {
    __shared__ unsigned short lds[16][128];
    int w = threadIdx.x >> 6, lane = threadIdx.x & 63;
    int c = lane & 15, q = lane >> 4;
    int rowbase = blockIdx.x * 16;
    int b = rowbase >> 10;
    int n0 = rowbase & 1023;

    bf16x8 xa[4];
    const float* xrow = x + (size_t)(rowbase + c) * 128;
#pragma unroll
    for (int ks = 0; ks < 4; ++ks)
        xa[ks] = load8f(xrow + ks * 32 + q * 8);

#pragma unroll
    for (int tt = 0; tt < 2; ++tt) {
        int t = w * 2 + tt;
        f32x4 acch = {0.f, 0.f, 0.f, 0.f};
        f32x4 accu = {0.f, 0.f, 0.f, 0.f};
        const unsigned short* wwrow = WwB + (t * 16 + c) * 128;
        const unsigned short* w2row = W2T + (t * 16 + c) * 128;
#pragma unroll
        for (int ks = 0; ks < 4; ++ks) {
            bf16x8 bw = *reinterpret_cast<const bf16x8*>(wwrow + ks * 32 + q * 8);
            bf16x8 b2 = *reinterpret_cast<const bf16x8*>(w2row + ks * 32 + q * 8);
            acch = __builtin_amdgcn_mfma_f32_16x16x32_bf16(xa[ks], bw, acch, 0, 0, 0);
            accu = __builtin_amdgcn_mfma_f32_16x16x32_bf16(xa[ks], b2, accu, 0, 0, 0);
        }
        float wb = Wb[t * 16 + c];
        float ub = wbA[t * 16 + c];
#pragma unroll
        for (int r = 0; r < 4; ++r) {
            int row = rowbase + q * 4 + r;
            unsigned short hv = f2b(acch[r] + wb);
            unsigned short uv = f2b(accu[r] + ub);
            h[(size_t)row * 128 + t * 16 + c] = hv;
            u[(size_t)row * 128 + t * 16 + c] = uv;
            lds[q * 4 + r][t * 16 + c] = hv;
        }
    }

    // fused kmask: wave w converts adj rows rowbase+4w..+4w+3 -> bitmask
    {
        const float* adjb = adj + ((size_t)(rowbase + w * 4)) * 1024;
#pragma unroll
        for (int r = 0; r < 4; ++r) {
#pragma unroll
            for (int g = 0; g < 16; ++g) {
                unsigned long long m = __ballot(adjb[(size_t)r * 1024 + g * 64 + lane] > 0.f);
                if (lane == 0) maskJ[(size_t)(rowbase + w * 4 + r) * 16 + g] = m;
            }
        }
    }

    __syncthreads();
    int tid = threadIdx.x;
    if (tid < 128) {
        int d = tid;
        unsigned int p[8];
#pragma unroll
        for (int k = 0; k < 8; ++k) {
            unsigned int v0 = lds[2 * k][d], v1 = lds[2 * k + 1][d];
            p[k] = v0 | (v1 << 16);
        }
        size_t basehT = ((size_t)(b * 128 + d)) * 1024 + n0;
        uint4* dst = reinterpret_cast<uint4*>(hT + basehT);
        dst[0] = make_uint4(p[0], p[1], p[2], p[3]);
        dst[1] = make_uint4(p[4], p[5], p[6], p[7]);
    }
}

// ========== FAST PATH ==========

// K2s: grid 512: block = 32 rows i, all 1024 j. 4 MFMA chains per tile.
__global__ __launch_bounds__(256) void k2_scores(
    const unsigned short* __restrict__ h, const unsigned short* __restrict__ u,
    const unsigned long long* __restrict__ maskJ,
    unsigned short* __restrict__ att, float* __restrict__ colpart) {
    __shared__ unsigned long long lmask[32][16];
    int w = threadIdx.x >> 6, lane = threadIdx.x & 63;
    int c = lane & 15, q = lane >> 4;
    int b = blockIdx.x >> 5;
    int iblk = blockIdx.x & 31;
    int i0 = iblk * 32;
    const unsigned short* hb = h + (size_t)b * N_ * D_;
    const unsigned short* ub = u + (size_t)b * N_ * D_;

    {
        int tid = threadIdx.x;
        lmask[tid >> 4][tid & 15] =
            maskJ[(size_t)(b * 1024 + i0 + (tid >> 4)) * 16 + (tid & 15)];
        lmask[16 + (tid >> 4)][tid & 15] =
            maskJ[(size_t)(b * 1024 + i0 + 16 + (tid >> 4)) * 16 + (tid & 15)];
    }
    __syncthreads();

    bf16x8 Au0[4], Ah0[4], Au1[4], Ah1[4];
#pragma unroll
    for (int ks = 0; ks < 4; ++ks) {
        Au0[ks] = *reinterpret_cast<const bf16x8*>(ub + (i0 + c) * 128 + ks * 32 + q * 8);
        Ah0[ks] = *reinterpret_cast<const bf16x8*>(hb + (i0 + c) * 128 + ks * 32 + q * 8);
        Au1[ks] = *reinterpret_cast<const bf16x8*>(ub + (i0 + 16 + c) * 128 + ks * 32 + q * 8);
        Ah1[ks] = *reinterpret_cast<const bf16x8*>(hb + (i0 + 16 + c) * 128 + ks * 32 + q * 8);
    }
    unsigned short* attrow = att + ((size_t)(b * 1024 + i0)) * 1024;
    float* cprow = colpart + ((size_t)(b * 32 + iblk)) * 1024;

    int jt0 = w * 16;                          // wave w: tiles jt0..jt0+15
#pragma unroll
    for (int t = 0; t < 16; ++t) {
        int jt = jt0 + t, j0 = jt * 16;
        bf16x8 Bh[4], Bu[4];
#pragma unroll
        for (int ks = 0; ks < 4; ++ks) {
            Bh[ks] = *reinterpret_cast<const bf16x8*>(hb + (j0 + c) * 128 + ks * 32 + q * 8);
            Bu[ks] = *reinterpret_cast<const bf16x8*>(ub + (j0 + c) * 128 + ks * 32 + q * 8);
        }
        f32x4 a00 = {0.f, 0.f, 0.f, 0.f};
        f32x4 a01 = {0.f, 0.f, 0.f, 0.f};
        f32x4 a10 = {0.f, 0.f, 0.f, 0.f};
        f32x4 a11 = {0.f, 0.f, 0.f, 0.f};
#pragma unroll
        for (int ks = 0; ks < 4; ++ks) {
            a00 = __builtin_amdgcn_mfma_f32_16x16x32_bf16(Au0[ks], Bh[ks], a00, 0, 0, 0);
            a01 = __builtin_amdgcn_mfma_f32_16x16x32_bf16(Ah0[ks], Bu[ks], a01, 0, 0, 0);
            a10 = __builtin_amdgcn_mfma_f32_16x16x32_bf16(Au1[ks], Bh[ks], a10, 0, 0, 0);
            a11 = __builtin_amdgcn_mfma_f32_16x16x32_bf16(Ah1[ks], Bu[ks], a11, 0, 0, 0);
        }
        int wd = jt >> 2, sh = (jt & 3) * 16;
        float colp = 0.f;
#pragma unroll
        for (int r = 0; r < 4; ++r) {
            float e0 = a00[r] + a01[r];         // e[i0+q*4+r][j0+c]
            float e1 = a10[r] + a11[r];         // e[i0+16+q*4+r][j0+c]
            bool m0 = (lmask[q * 4 + r][wd] >> (sh + c)) & 1ull;
            bool m1 = (lmask[16 + q * 4 + r][wd] >> (sh + c)) & 1ull;
            float ex0 = m0 ? __expf(clamp60(e0)) : 0.f;
            float ex1 = m1 ? __expf(clamp60(e1)) : 0.f;
            colp += (m0 ? ex0 : 1.0f) + (m1 ? ex1 : 1.0f);
            attrow[(size_t)(q * 4 + r) * 1024 + j0 + c] = f2b(ex0);
            attrow[(size_t)(16 + q * 4 + r) * 1024 + j0 + c] = f2b(ex1);
        }
        colp += __shfl_xor(colp, 16, 64);
        colp += __shfl_xor(colp, 32, 64);
        if (q == 0) cprow[j0 + c] = colp;
    }
}

// K2b: rl0 = 1/sum(colpart)
__global__ __launch_bounds__(256) void k2b_recip(
    const float* __restrict__ colpart, float* __restrict__ rl0) {
    int g = blockIdx.x * 256 + threadIdx.x;   // 0..16383
    int b = g >> 10, j = g & 1023;
    float s = 0.f;
    const float* p = colpart + (size_t)b * 32 * 1024 + j;
    for (int ib = 0; ib < 32; ++ib) s += p[(size_t)ib * 1024];
    rl0[g] = 1.0f / s;
}

// K3g: pure GEMM h' = relu((att*rl0) @ h) + gates. att is bf16.
__global__ __launch_bounds__(256) void k3_gemm(
    const unsigned short* __restrict__ att, const float* __restrict__ rl0,
    const unsigned short* __restrict__ hT, const float* __restrict__ x,
    const float* __restrict__ wi_u, const float* __restrict__ wi_x,
    const float* __restrict__ wf_u, const float* __restrict__ wf_x,
    const float* __restrict__ wo_u, const float* __restrict__ wo_x,
    float* __restrict__ out) {
    __shared__ float red[4][16][129];
    int w = threadIdx.x >> 6, lane = threadIdx.x & 63;
    int c = lane & 15, q = lane >> 4;
    int b = blockIdx.x >> 6;
    int i0 = (blockIdx.x & 63) * 16;
    const unsigned short* attrow = att + ((size_t)(b * 1024 + i0 + c)) * 1024;
    const unsigned short* hTb = hT + (size_t)b * 128 * 1024;
    const float* rl0b = rl0 + b * 1024;

    f32x4 hp[8];
#pragma unroll
    for (int t = 0; t < 8; ++t) hp[t] = (f32x4){0.f, 0.f, 0.f, 0.f};

#pragma unroll
    for (int tt = 0; tt < 8; ++tt) {
        int jp = w * 8 + tt;
        int jb = jp * 32 + q * 8;
        bf16x8 eraw = *reinterpret_cast<const bf16x8*>(attrow + jb);
        float4 r0 = *reinterpret_cast<const float4*>(rl0b + jb);
        float4 r1 = *reinterpret_cast<const float4*>(rl0b + jb + 4);
        bf16x8 a;
        a[0] = (short)f2b(b2f((unsigned short)eraw[0]) * r0.x);
        a[1] = (short)f2b(b2f((unsigned short)eraw[1]) * r0.y);
        a[2] = (short)f2b(b2f((unsigned short)eraw[2]) * r0.z);
        a[3] = (short)f2b(b2f((unsigned short)eraw[3]) * r0.w);
        a[4] = (short)f2b(b2f((unsigned short)eraw[4]) * r1.x);
        a[5] = (short)f2b(b2f((unsigned short)eraw[5]) * r1.y);
        a[6] = (short)f2b(b2f((unsigned short)eraw[6]) * r1.z);
        a[7] = (short)f2b(b2f((unsigned short)eraw[7]) * r1.w);
#pragma unroll
        for (int t = 0; t < 8; ++t) {
            bf16x8 bt = *reinterpret_cast<const bf16x8*>(
                hTb + (size_t)(t * 16 + c) * 1024 + jp * 32 + q * 8);
            hp[t] = __builtin_amdgcn_mfma_f32_16x16x32_bf16(a, bt, hp[t], 0, 0, 0);
        }
    }

#pragma unroll
    for (int t = 0; t < 8; ++t)
#pragma unroll
        for (int r = 0; r < 4; ++r)
            red[w][q * 4 + r][t * 16 + c] = hp[t][r];
    __syncthreads();
    if (w != 0) return;

#pragma unroll
    for (int t = 0; t < 8; ++t)
#pragma unroll
        for (int r = 0; r < 4; ++r)
            hp[t][r] = red[0][q * 4 + r][t * 16 + c] + red[1][q * 4 + r][t * 16 + c]
                     + red[2][q * 4 + r][t * 16 + c] + red[3][q * 4 + r][t * 16 + c];

    float xv[8][4];
#pragma unroll
    for (int t = 0; t < 8; ++t)
#pragma unroll
        for (int r = 0; r < 4; ++r) {
            hp[t][r] = fmaxf(hp[t][r], 0.f);
            xv[t][r] = x[(size_t)(b * 1024 + i0 + q * 4 + r) * 128 + t * 16 + c];
        }
    float wiu[8], wix[8], wfu[8], wfx[8], wou[8], wox[8];
#pragma unroll
    for (int t = 0; t < 8; ++t) {
        wiu[t] = wi_u[t * 16 + c]; wix[t] = wi_x[t * 16 + c];
        wfu[t] = wf_u[t * 16 + c]; wfx[t] = wf_x[t * 16 + c];
        wou[t] = wo_u[t * 16 + c]; wox[t] = wo_x[t * 16 + c];
    }
#pragma unroll
    for (int r = 0; r < 4; ++r) {
        float zi = 0.f, zf = 0.f, zo = 0.f;
#pragma unroll
        for (int t = 0; t < 8; ++t) {
            zi += hp[t][r] * wiu[t] + xv[t][r] * wix[t];
            zf += hp[t][r] * wfu[t] + xv[t][r] * wfx[t];
            zo += hp[t][r] * wou[t] + xv[t][r] * wox[t];
        }
        zi += __shfl_xor(zi, 1, 64); zi += __shfl_xor(zi, 2, 64);
        zi += __shfl_xor(zi, 4, 64); zi += __shfl_xor(zi, 8, 64);
        zf += __shfl_xor(zf, 1, 64); zf += __shfl_xor(zf, 2, 64);
        zf += __shfl_xor(zf, 4, 64); zf += __shfl_xor(zf, 8, 64);
        zo += __shfl_xor(zo, 1, 64); zo += __shfl_xor(zo, 2, 64);
        zo += __shfl_xor(zo, 4, 64); zo += __shfl_xor(zo, 8, 64);
        float ic = 1.f / (1.f + __expf(-zi));
        float fc = 1.f / (1.f + __expf(-zf));
        float oc = 1.f / (1.f + __expf(-zo));
#pragma unroll
        for (int t = 0; t < 8; ++t) {
            float zz = ic * hp[t][r] + fc * xv[t][r];
            float th = 1.f - 2.f / (__expf(2.f * zz) + 1.f);
            out[(size_t)(b * 1024 + i0 + q * 4 + r) * 128 + t * 16 + c] = oc * th;
        }
    }
}

// ========== FALLBACK PATH (round-4, proven; needs separate kmask + k1 w/o adj) ==========
__global__ __launch_bounds__(256) void k1_hu_nb(
    const float* __restrict__ x, const unsigned short* __restrict__ WwB,
    const float* __restrict__ Wb, const unsigned short* __restrict__ W2T,
    const float* __restrict__ wbA,
    unsigned short* __restrict__ h, unsigned short* __restrict__ u,
    unsigned short* __restrict__ hT) {
    __shared__ unsigned short lds[16][128];
    int w = threadIdx.x >> 6, lane = threadIdx.x & 63;
    int c = lane & 15, q = lane >> 4;
    int rowbase = blockIdx.x * 16;
    int b = rowbase >> 10;
    int n0 = rowbase & 1023;
    bf16x8 xa[4];
    const float* xrow = x + (size_t)(rowbase + c) * 128;
#pragma unroll
    for (int ks = 0; ks < 4; ++ks)
        xa[ks] = load8f(xrow + ks * 32 + q * 8);
#pragma unroll
    for (int tt = 0; tt < 2; ++tt) {
        int t = w * 2 + tt;
        f32x4 acch = {0.f, 0.f, 0.f, 0.f};
        f32x4 accu = {0.f, 0.f, 0.f, 0.f};
        const unsigned short* wwrow = WwB + (t * 16 + c) * 128;
        const unsigned short* w2row = W2T + (t * 16 + c) * 128;
#pragma unroll
        for (int ks = 0; ks < 4; ++ks) {
            bf16x8 bw = *reinterpret_cast<const bf16x8*>(wwrow + ks * 32 + q * 8);
            bf16x8 b2 = *reinterpret_cast<const bf16x8*>(w2row + ks * 32 + q * 8);
            acch = __builtin_amdgcn_mfma_f32_16x16x32_bf16(xa[ks], bw, acch, 0, 0, 0);
            accu = __builtin_amdgcn_mfma_f32_16x16x32_bf16(xa[ks], b2, accu, 0, 0, 0);
        }
        float wb = Wb[t * 16 + c];
        float ub = wbA[t * 16 + c];
#pragma unroll
        for (int r = 0; r < 4; ++r) {
            int row = rowbase + q * 4 + r;
            unsigned short hv = f2b(acch[r] + wb);
            unsigned short uv = f2b(accu[r] + ub);
            h[(size_t)row * 128 + t * 16 + c] = hv;
            u[(size_t)row * 128 + t * 16 + c] = uv;
            lds[q * 4 + r][t * 16 + c] = hv;
        }
    }
    __syncthreads();
    int tid = threadIdx.x;
    if (tid < 128) {
        int d = tid;
        unsigned int p[8];
#pragma unroll
        for (int k = 0; k < 8; ++k) {
            unsigned int v0 = lds[2 * k][d], v1 = lds[2 * k + 1][d];
            p[k] = v0 | (v1 << 16);
        }
        size_t basehT = ((size_t)(b * 128 + d)) * 1024 + n0;
        uint4* dst = reinterpret_cast<uint4*>(hT + basehT);
        dst[0] = make_uint4(p[0], p[1], p[2], p[3]);
        dst[1] = make_uint4(p[4], p[5], p[6], p[7]);
    }
}

__global__ __launch_bounds__(256) void k2_stats(
    const unsigned short* __restrict__ h, const unsigned short* __restrict__ u,
    const unsigned long long* __restrict__ maskJ, float* __restrict__ rl0) {
    int w = threadIdx.x >> 6, lane = threadIdx.x & 63;
    int c = lane & 15, q = lane >> 4;
    int b = blockIdx.x >> 6;
    int j0 = (blockIdx.x & 63) * 16;
    const unsigned short* hb = h + (size_t)b * N_ * D_;
    const unsigned short* ub = u + (size_t)b * N_ * D_;
    bf16x8 Bh[4], Bu[4];
#pragma unroll
    for (int ks = 0; ks < 4; ++ks) {
        Bh[ks] = *reinterpret_cast<const bf16x8*>(hb + (j0 + c) * 128 + ks * 32 + q * 8);
        Bu[ks] = *reinterpret_cast<const bf16x8*>(ub + (j0 + c) * 128 + ks * 32 + q * 8);
    }
    float colsum = 0.f;
    const unsigned long long* mrow = maskJ + (size_t)b * 1024 * 16 + (j0 >> 6);
    int jb = j0 & 63;
    for (int it = w; it < 64; it += 4) {
        int i0 = it * 16;
        f32x4 acc = {0.f, 0.f, 0.f, 0.f};
#pragma unroll
        for (int ks = 0; ks < 4; ++ks) {
            bf16x8 au = *reinterpret_cast<const bf16x8*>(ub + (i0 + c) * 128 + ks * 32 + q * 8);
            bf16x8 ah = *reinterpret_cast<const bf16x8*>(hb + (i0 + c) * 128 + ks * 32 + q * 8);
            acc = __builtin_amdgcn_mfma_f32_16x16x32_bf16(au, Bh[ks], acc, 0, 0, 0);
            acc = __builtin_amdgcn_mfma_f32_16x16x32_bf16(ah, Bu[ks], acc, 0, 0, 0);
        }
#pragma unroll
        for (int r = 0; r < 4; ++r) {
            int i = i0 + q * 4 + r;
            unsigned long long mword = mrow[(size_t)i * 16];
            bool m = (mword >> (jb + c)) & 1ull;
            colsum += m ? __expf(clamp60(acc[r])) : 1.0f;
        }
    }
    colsum += __shfl_xor(colsum, 16, 64);
    colsum += __shfl_xor(colsum, 32, 64);
    __shared__ float part[4][16];
    if (lane < 16) part[w][lane] = colsum;
    __syncthreads();
    if (threadIdx.x < 16) {
        float s = part[0][threadIdx.x] + part[1][threadIdx.x]
                + part[2][threadIdx.x] + part[3][threadIdx.x];
        rl0[b * 1024 + j0 + threadIdx.x] = 1.0f / s;
    }
}

__global__ __launch_bounds__(256) void k3_fused(
    const unsigned short* __restrict__ h, const unsigned short* __restrict__ uu,
    const unsigned long long* __restrict__ maskJ, const float* __restrict__ rl0,
    const unsigned short* __restrict__ hT, const float* __restrict__ x,
    const float* __restrict__ wi_u, const float* __restrict__ wi_x,
    const float* __restrict__ wf_u, const float* __restrict__ wf_x,
    const float* __restrict__ wo_u, const float* __restrict__ wo_x,
    float* __restrict__ out) {
    __shared__ float red[4][16][129];
    int w = threadIdx.x >> 6, lane = threadIdx.x & 63;
    int c = lane & 15, q = lane >> 4;
    int b = blockIdx.x >> 6;
    int i0 = (blockIdx.x & 63) * 16;
    const unsigned short* hb = h + (size_t)b * N_ * D_;
    const unsigned short* ub = uu + (size_t)b * N_ * D_;
    const unsigned short* hTb = hT + (size_t)b * 128 * 1024;
    const unsigned long long* mrowI = maskJ + (size_t)(b * 1024 + i0 + c) * 16;
    const float* rl0b = rl0 + b * 1024;
    bf16x8 Bh[4], Bu[4];
#pragma unroll
    for (int ks = 0; ks < 4; ++ks) {
        Bh[ks] = *reinterpret_cast<const bf16x8*>(hb + (i0 + c) * 128 + ks * 32 + q * 8);
        Bu[ks] = *reinterpret_cast<const bf16x8*>(ub + (i0 + c) * 128 + ks * 32 + q * 8);
    }
    f32x4 hp[8];
#pragma unroll
    for (int t = 0; t < 8; ++t) hp[t] = (f32x4){0.f, 0.f, 0.f, 0.f};
    for (int jp = w; jp < 32; jp += 4) {
        int j0 = jp * 32;
        unsigned long long mw64 = mrowI[jp >> 1];
        unsigned int mbits = (unsigned int)(mw64 >> ((jp & 1) * 32));
        unsigned int u00, u01, u10, u11;
#pragma unroll
        for (int s = 0; s < 2; ++s) {
            int js = j0 + s * 16;
            f32x4 acc = {0.f, 0.f, 0.f, 0.f};
#pragma unroll
            for (int ks = 0; ks < 4; ++ks) {
                bf16x8 au = *reinterpret_cast<const bf16x8*>(ub + (js + c) * 128 + ks * 32 + q * 8);
                bf16x8 ah = *reinterpret_cast<const bf16x8*>(hb + (js + c) * 128 + ks * 32 + q * 8);
                acc = __builtin_amdgcn_mfma_f32_16x16x32_bf16(au, Bh[ks], acc, 0, 0, 0);
                acc = __builtin_amdgcn_mfma_f32_16x16x32_bf16(ah, Bu[ks], acc, 0, 0, 0);
            }
            float4 rv = *reinterpret_cast<const float4*>(rl0b + js + q * 4);
            int bb = s * 16 + q * 4;
            float a0 = ((mbits >> (bb + 0)) & 1u) ? __expf(clamp60(acc[0])) * rv.x : 0.f;
            float a1 = ((mbits >> (bb + 1)) & 1u) ? __expf(clamp60(acc[1])) * rv.y : 0.f;
            float a2 = ((mbits >> (bb + 2)) & 1u) ? __expf(clamp60(acc[2])) * rv.z : 0.f;
            float a3 = ((mbits >> (bb + 3)) & 1u) ? __expf(clamp60(acc[3])) * rv.w : 0.f;
            unsigned int p0 = (unsigned int)f2b(a0) | ((unsigned int)f2b(a1) << 16);
            unsigned int p1 = (unsigned int)f2b(a2) | ((unsigned int)f2b(a3) << 16);
            if (s == 0) { u00 = p0; u01 = p1; } else { u10 = p0; u11 = p1; }
        }
        int la = c + 32 * (q & 1);
        int lb = la + 16;
        unsigned int x0 = __shfl((int)u00, la, 64), x1 = __shfl((int)u01, la, 64);
        unsigned int x2 = __shfl((int)u00, lb, 64), x3 = __shfl((int)u01, lb, 64);
        unsigned int y0 = __shfl((int)u10, la, 64), y1 = __shfl((int)u11, la, 64);
        unsigned int y2 = __shfl((int)u10, lb, 64), y3 = __shfl((int)u11, lb, 64);
        bool hiq = (q >> 1) != 0;
        union { unsigned int ui[4]; bf16x8 v; } att;
        att.ui[0] = hiq ? y0 : x0;
        att.ui[1] = hiq ? y1 : x1;
        att.ui[2] = hiq ? y2 : x2;
        att.ui[3] = hiq ? y3 : x3;
#pragma unroll
        for (int t = 0; t < 8; ++t) {
            bf16x8 bt = *reinterpret_cast<const bf16x8*>(
                hTb + (size_t)(t * 16 + c) * 1024 + j0 + q * 8);
            hp[t] = __builtin_amdgcn_mfma_f32_16x16x32_bf16(att.v, bt, hp[t], 0, 0, 0);
        }
    }
#pragma unroll
    for (int t = 0; t < 8; ++t)
#pragma unroll
        for (int r = 0; r < 4; ++r)
            red[w][q * 4 + r][t * 16 + c] = hp[t][r];
    __syncthreads();
    if (w != 0) return;
#pragma unroll
    for (int t = 0; t < 8; ++t)
#pragma unroll
        for (int r = 0; r < 4; ++r)
            hp[t][r] = red[0][q * 4 + r][t * 16 + c] + red[1][q * 4 + r][t * 16 + c]
                     + red[2][q * 4 + r][t * 16 + c] + red[3][q * 4 + r][t * 16 + c];
    float xv[8][4];
#pragma unroll
    for (int t = 0; t < 8; ++t)
#pragma unroll
        for (int r = 0; r < 4; ++r) {
            hp[t][r] = fmaxf(hp[t][r], 0.f);
            xv[t][r] = x[(size_t)(b * 1024 + i0 + q * 4 + r) * 128 + t * 16 + c];
        }
    float wiu[8], wix[8], wfu[8], wfx[8], wou[8], wox[8];
#pragma unroll
    for (int t = 0; t < 8; ++t) {
        wiu[t] = wi_u[t * 16 + c]; wix[t] = wi_x[t * 16 + c];
        wfu[t] = wf_u[t * 16 + c]; wfx[t] = wf_x[t * 16 + c];
        wou[t] = wo_u[t * 16 + c]; wox[t] = wo_x[t * 16 + c];
    }
#pragma unroll
    for (int r = 0; r < 4; ++r) {
        float zi = 0.f, zf = 0.f, zo = 0.f;
#pragma unroll
        for (int t = 0; t < 8; ++t) {
            zi += hp[t][r] * wiu[t] + xv[t][r] * wix[t];
            zf += hp[t][r] * wfu[t] + xv[t][r] * wfx[t];
            zo += hp[t][r] * wou[t] + xv[t][r] * wox[t];
        }
        zi += __shfl_xor(zi, 1, 64); zi += __shfl_xor(zi, 2, 64);
        zi += __shfl_xor(zi, 4, 64); zi += __shfl_xor(zi, 8, 64);
        zf += __shfl_xor(zf, 1, 64); zf += __shfl_xor(zf, 2, 64);
        zf += __shfl_xor(zf, 4, 64); zf += __shfl_xor(zf, 8, 64);
        zo += __shfl_xor(zo, 1, 64); zo += __shfl_xor(zo, 2, 64);
        zo += __shfl_xor(zo, 4, 64); zo += __shfl_xor(zo, 8, 64);
        float ic = 1.f / (1.f + __expf(-zi));
        float fc = 1.f / (1.f + __expf(-zf));
        float oc = 1.f / (1.f + __expf(-zo));
#pragma unroll
        for (int t = 0; t < 8; ++t) {
            float zz = ic * hp[t][r] + fc * xv[t][r];
            float th = 1.f - 2.f / (__expf(2.f * zz) + 1.f);
            out[(size_t)(b * 1024 + i0 + q * 4 + r) * 128 + t * 16 + c] = oc * th;
        }
    }
}

extern "C" void kernel_launch(void* const* d_in, const int* in_sizes, int n_in,
                              void* d_out, int out_size, void* d_ws, size_t ws_size,
                              hipStream_t stream) {
    const float* x    = (const float*)d_in[0];
    const float* adj  = (const float*)d_in[1];
    const float* Ww   = (const float*)d_in[2];
    const float* Wb   = (const float*)d_in[3];
    const float* A    = (const float*)d_in[4];
    const float* wi_u = (const float*)d_in[5];
    const float* wi_x = (const float*)d_in[6];
    const float* wf_u = (const float*)d_in[7];
    const float* wf_x = (const float*)d_in[8];
    const float* wo_u = (const float*)d_in[9];
    const float* wo_x = (const float*)d_in[10];
    float* out = (float*)d_out;
    char* ws = (char*)d_ws;

    if (ws_size >= (56ull << 20)) {
        // fast path layout
        unsigned short* WwB = (unsigned short*)(ws);                      // 32K
        unsigned short* W2T = (unsigned short*)(ws + (32u << 10));        // 32K
        float* wbA          = (float*)(ws + (64u << 10));                 // 512B
        float* rl0          = (float*)(ws + (128u << 10));                // 64K
        unsigned long long* maskJ = (unsigned long long*)(ws + (256u << 10)); // 2M
        float* colpart      = (float*)(ws + (4ull << 20));                // 2M
        unsigned short* h   = (unsigned short*)(ws + (8ull << 20));       // 4M
        unsigned short* u   = (unsigned short*)(ws + (12ull << 20));      // 4M
        unsigned short* hT  = (unsigned short*)(ws + (16ull << 20));      // 4M
        unsigned short* att = (unsigned short*)(ws + (20ull << 20));      // 32M

        k0_w2t<<<64, 256, 0, stream>>>(Ww, Wb, A, WwB, W2T, wbA);
        k1_hu<<<1024, 256, 0, stream>>>(x, WwB, Wb, W2T, wbA, adj, h, u, hT, maskJ);
        k2_scores<<<512, 256, 0, stream>>>(h, u, maskJ, att, colpart);
        k2b_recip<<<64, 256, 0, stream>>>(colpart, rl0);
        k3_gemm<<<1024, 256, 0, stream>>>(att, rl0, hT, x,
                                          wi_u, wi_x, wf_u, wf_x, wo_u, wo_x, out);
    } else {
        // fallback: round-4 layout + kernels
        unsigned short* WwB = (unsigned short*)(ws);
        unsigned short* W2T = (unsigned short*)(ws + (32u << 10));
        float* wbA          = (float*)(ws + (64u << 10));
        float* rl0          = (float*)(ws + (128u << 10));
        unsigned short* h   = (unsigned short*)(ws + (1u << 20));
        unsigned short* u   = (unsigned short*)(ws + (5u << 20));
        unsigned short* hT  = (unsigned short*)(ws + (9u << 20));
        unsigned long long* maskJ = (unsigned long long*)(ws + (13u << 20));

        k0_w2t<<<64, 256, 0, stream>>>(Ww, Wb, A, WwB, W2T, wbA);
        kmask<<<16384, 256, 0, stream>>>(adj, maskJ);
        k1_hu_nb<<<1024, 256, 0, stream>>>(x, WwB, Wb, W2T, wbA, h, u, hT);
        k2_stats<<<1024, 256, 0, stream>>>(h, u, maskJ, rl0);
        k3_fused<<<1024, 256, 0, stream>>>(h, u, maskJ, rl0, hT, x,
                                           wi_u, wi_x, wf_u, wf_x, wo_u, wo_x, out);
    }
}

// Round 9
// 224.886 us; speedup vs baseline: 1.2145x; 1.0963x over previous
//
#include <hip/hip_runtime.h>

// GAT_gate: B=16, N=1024, D=128. FP32 I/O; bf16 MFMA internally, fp32 accum.
//
// Fast path (ws >= 56MB):
//  K0:    WwB = bf16(Ww); W2T = bf16(A^T Ww); wbA = Wb@A (fp32)
//  kmask: adj (64MB fp32) -> 2MB bitmask, standalone wide grid (ballot inside a
//         compute kernel serializes loads -- measured 60us fused vs 14us here).
//  K1:    h = x@Ww^T+Wb ; u = x@W2T^T+wbA -> h,u bf16; hT bf16 [b][d][n]
//  K2s:   grid 512: block = 32 rows i x all j. 16 A-frags hoisted; per j-tile
//         4 independent MFMA chains (2 row-groups x 2 products) = 16 MFMAs.
//         att = mask?exp(e):0 -> bf16 (32MB); partial colsums (32 rows/blk).
//  K2b:   rl0[j] = 1 / sum_iblk colpart
//  K3g:   pure GEMM h' = relu((att*rl0[j]) @ h) vs hT + LSTM-gate epilogue.
// Fallback (ws < 56MB): round-4 kernels (kmask + k2_stats + k3_fused).

#define B_ 16
#define N_ 1024
#define D_ 128

typedef __attribute__((ext_vector_type(8))) short bf16x8;
typedef __attribute__((ext_vector_type(4))) float f32x4;

__device__ __forceinline__ float b2f(unsigned short u) {
    union { unsigned int i; float f; } v; v.i = ((unsigned int)u) << 16; return v.f;
}
__device__ __forceinline__ unsigned short f2b(float f) {
    union { float f; unsigned int i; } v; v.f = f;
    unsigned int x = v.i;
    return (unsigned short)((x + 0x7fffu + ((x >> 16) & 1u)) >> 16);
}
__device__ __forceinline__ float clamp60(float v) {
    return fminf(fmaxf(v, -60.f), 60.f);
}
__device__ __forceinline__ bf16x8 load8f(const float* p) {
    float4 a = *reinterpret_cast<const float4*>(p);
    float4 b = *reinterpret_cast<const float4*>(p + 4);
    bf16x8 v;
    v[0] = (short)f2b(a.x); v[1] = (short)f2b(a.y);
    v[2] = (short)f2b(a.z); v[3] = (short)f2b(a.w);
    v[4] = (short)f2b(b.x); v[5] = (short)f2b(b.y);
    v[6] = (short)f2b(b.z); v[7] = (short)f2b(b.w);
    return v;
}

// ---------------- K0: fold weights ----------------
__global__ __launch_bounds__(256) void k0_w2t(
    const float* __restrict__ Ww, const float* __restrict__ Wb,
    const float* __restrict__ A, unsigned short* __restrict__ WwB,
    unsigned short* __restrict__ W2T, float* __restrict__ wbA) {
    int t = blockIdx.x * 256 + threadIdx.x;
    int l = t >> 7, f = t & 127;
    float acc = 0.f;
    for (int d = 0; d < 128; ++d)
        acc += A[d * 128 + l] * Ww[d * 128 + f];
    W2T[l * 128 + f] = f2b(acc);
    WwB[t] = f2b(Ww[t]);
    if (blockIdx.x == 0 && threadIdx.x < 128) {
        float s = 0.f;
        for (int d = 0; d < 128; ++d) s += Wb[d] * A[d * 128 + threadIdx.x];
        wbA[threadIdx.x] = s;
    }
}

// ---------------- kmask: adj -> bitmask (standalone, wide grid) ----------------
__global__ __launch_bounds__(256) void kmask(
    const float* __restrict__ adj, unsigned long long* __restrict__ maskJ) {
    int w = threadIdx.x >> 6, lane = threadIdx.x & 63;
    size_t base = ((size_t)blockIdx.x * 4 + w) * 256;
    unsigned long long w0 = __ballot(adj[base + 0 * 64 + lane] > 0.f);
    unsigned long long w1 = __ballot(adj[base + 1 * 64 + lane] > 0.f);
    unsigned long long w2 = __ballot(adj[base + 2 * 64 + lane] > 0.f);
    unsigned long long w3 = __ballot(adj[base + 3 * 64 + lane] > 0.f);
    unsigned long long o = lane == 0 ? w0 : lane == 1 ? w1 : lane == 2 ? w2 : w3;
    if (lane < 4) maskJ[(base >> 6) + lane] = o;
}

// ---------------- K1: h, u, hT ----------------
__global__ __launch_bounds__(256) void k1_hu(
    const float* __restrict__ x, const unsigned short* __restrict__ WwB,
    const float* __restrict__ Wb, const unsigned short* __restrict__ W2T,
    const float* __restrict__ wbA,
    unsigned short* __restrict__ h, unsigned short* __restrict__ u,
    unsigned short* __restrict__ hT) {
    __shared__ unsigned short lds[16][128];
    int w = threadIdx.x >> 6, lane = threadIdx.x & 63;
    int c = lane & 15, q = lane >> 4;
    int rowbase = blockIdx.x * 16;
    int b = rowbase >> 10;
    int n0 = rowbase & 1023;

    bf16x8 xa[4];
    const float* xrow = x + (size_t)(rowbase + c) * 128;
#pragma unroll
    for (int ks = 0; ks < 4; ++ks)
        xa[ks] = load8f(xrow + ks * 32 + q * 8);

#pragma unroll
    for (int tt = 0; tt < 2; ++tt) {
        int t = w * 2 + tt;
        f32x4 acch = {0.f, 0.f, 0.f, 0.f};
        f32x4 accu = {0.f, 0.f, 0.f, 0.f};
        const unsigned short* wwrow = WwB + (t * 16 + c) * 128;
        const unsigned short* w2row = W2T + (t * 16 + c) * 128;
#pragma unroll
        for (int ks = 0; ks < 4; ++ks) {
            bf16x8 bw = *reinterpret_cast<const bf16x8*>(wwrow + ks * 32 + q * 8);
            bf16x8 b2 = *reinterpret_cast<const bf16x8*>(w2row + ks * 32 + q * 8);
            acch = __builtin_amdgcn_mfma_f32_16x16x32_bf16(xa[ks], bw, acch, 0, 0, 0);
            accu = __builtin_amdgcn_mfma_f32_16x16x32_bf16(xa[ks], b2, accu, 0, 0, 0);
        }
        float wb = Wb[t * 16 + c];
        float ub = wbA[t * 16 + c];
#pragma unroll
        for (int r = 0; r < 4; ++r) {
            int row = rowbase + q * 4 + r;
            unsigned short hv = f2b(acch[r] + wb);
            unsigned short uv = f2b(accu[r] + ub);
            h[(size_t)row * 128 + t * 16 + c] = hv;
            u[(size_t)row * 128 + t * 16 + c] = uv;
            lds[q * 4 + r][t * 16 + c] = hv;
        }
    }
    __syncthreads();
    int tid = threadIdx.x;
    if (tid < 128) {
        int d = tid;
        unsigned int p[8];
#pragma unroll
        for (int k = 0; k < 8; ++k) {
            unsigned int v0 = lds[2 * k][d], v1 = lds[2 * k + 1][d];
            p[k] = v0 | (v1 << 16);
        }
        size_t basehT = ((size_t)(b * 128 + d)) * 1024 + n0;
        uint4* dst = reinterpret_cast<uint4*>(hT + basehT);
        dst[0] = make_uint4(p[0], p[1], p[2], p[3]);
        dst[1] = make_uint4(p[4], p[5], p[6], p[7]);
    }
}

// ========== FAST PATH ==========

// K2s: grid 512: block = 32 rows i, all 1024 j. 4 MFMA chains per tile.
__global__ __launch_bounds__(256) void k2_scores(
    const unsigned short* __restrict__ h, const unsigned short* __restrict__ u,
    const unsigned long long* __restrict__ maskJ,
    unsigned short* __restrict__ att, float* __restrict__ colpart) {
    __shared__ unsigned long long lmask[32][16];
    int w = threadIdx.x >> 6, lane = threadIdx.x & 63;
    int c = lane & 15, q = lane >> 4;
    int b = blockIdx.x >> 5;
    int iblk = blockIdx.x & 31;
    int i0 = iblk * 32;
    const unsigned short* hb = h + (size_t)b * N_ * D_;
    const unsigned short* ub = u + (size_t)b * N_ * D_;

    {
        int tid = threadIdx.x;
        lmask[tid >> 4][tid & 15] =
            maskJ[(size_t)(b * 1024 + i0 + (tid >> 4)) * 16 + (tid & 15)];
        lmask[16 + (tid >> 4)][tid & 15] =
            maskJ[(size_t)(b * 1024 + i0 + 16 + (tid >> 4)) * 16 + (tid & 15)];
    }
    __syncthreads();

    bf16x8 Au0[4], Ah0[4], Au1[4], Ah1[4];
#pragma unroll
    for (int ks = 0; ks < 4; ++ks) {
        Au0[ks] = *reinterpret_cast<const bf16x8*>(ub + (i0 + c) * 128 + ks * 32 + q * 8);
        Ah0[ks] = *reinterpret_cast<const bf16x8*>(hb + (i0 + c) * 128 + ks * 32 + q * 8);
        Au1[ks] = *reinterpret_cast<const bf16x8*>(ub + (i0 + 16 + c) * 128 + ks * 32 + q * 8);
        Ah1[ks] = *reinterpret_cast<const bf16x8*>(hb + (i0 + 16 + c) * 128 + ks * 32 + q * 8);
    }
    unsigned short* attrow = att + ((size_t)(b * 1024 + i0)) * 1024;
    float* cprow = colpart + ((size_t)(b * 32 + iblk)) * 1024;

    int jt0 = w * 16;                          // wave w: tiles jt0..jt0+15
#pragma unroll
    for (int t = 0; t < 16; ++t) {
        int jt = jt0 + t, j0 = jt * 16;
        bf16x8 Bh[4], Bu[4];
#pragma unroll
        for (int ks = 0; ks < 4; ++ks) {
            Bh[ks] = *reinterpret_cast<const bf16x8*>(hb + (j0 + c) * 128 + ks * 32 + q * 8);
            Bu[ks] = *reinterpret_cast<const bf16x8*>(ub + (j0 + c) * 128 + ks * 32 + q * 8);
        }
        f32x4 a00 = {0.f, 0.f, 0.f, 0.f};
        f32x4 a01 = {0.f, 0.f, 0.f, 0.f};
        f32x4 a10 = {0.f, 0.f, 0.f, 0.f};
        f32x4 a11 = {0.f, 0.f, 0.f, 0.f};
#pragma unroll
        for (int ks = 0; ks < 4; ++ks) {
            a00 = __builtin_amdgcn_mfma_f32_16x16x32_bf16(Au0[ks], Bh[ks], a00, 0, 0, 0);
            a01 = __builtin_amdgcn_mfma_f32_16x16x32_bf16(Ah0[ks], Bu[ks], a01, 0, 0, 0);
            a10 = __builtin_amdgcn_mfma_f32_16x16x32_bf16(Au1[ks], Bh[ks], a10, 0, 0, 0);
            a11 = __builtin_amdgcn_mfma_f32_16x16x32_bf16(Ah1[ks], Bu[ks], a11, 0, 0, 0);
        }
        int wd = jt >> 2, sh = (jt & 3) * 16;
        float colp = 0.f;
#pragma unroll
        for (int r = 0; r < 4; ++r) {
            float e0 = a00[r] + a01[r];         // e[i0+q*4+r][j0+c]
            float e1 = a10[r] + a11[r];         // e[i0+16+q*4+r][j0+c]
            bool m0 = (lmask[q * 4 + r][wd] >> (sh + c)) & 1ull;
            bool m1 = (lmask[16 + q * 4 + r][wd] >> (sh + c)) & 1ull;
            float ex0 = m0 ? __expf(clamp60(e0)) : 0.f;
            float ex1 = m1 ? __expf(clamp60(e1)) : 0.f;
            colp += (m0 ? ex0 : 1.0f) + (m1 ? ex1 : 1.0f);
            attrow[(size_t)(q * 4 + r) * 1024 + j0 + c] = f2b(ex0);
            attrow[(size_t)(16 + q * 4 + r) * 1024 + j0 + c] = f2b(ex1);
        }
        colp += __shfl_xor(colp, 16, 64);
        colp += __shfl_xor(colp, 32, 64);
        if (q == 0) cprow[j0 + c] = colp;
    }
}

// K2b: rl0 = 1/sum(colpart)
__global__ __launch_bounds__(256) void k2b_recip(
    const float* __restrict__ colpart, float* __restrict__ rl0) {
    int g = blockIdx.x * 256 + threadIdx.x;   // 0..16383
    int b = g >> 10, j = g & 1023;
    float s = 0.f;
    const float* p = colpart + (size_t)b * 32 * 1024 + j;
    for (int ib = 0; ib < 32; ++ib) s += p[(size_t)ib * 1024];
    rl0[g] = 1.0f / s;
}

// K3g: pure GEMM h' = relu((att*rl0) @ h) + gates. att is bf16.
__global__ __launch_bounds__(256) void k3_gemm(
    const unsigned short* __restrict__ att, const float* __restrict__ rl0,
    const unsigned short* __restrict__ hT, const float* __restrict__ x,
    const float* __restrict__ wi_u, const float* __restrict__ wi_x,
    const float* __restrict__ wf_u, const float* __restrict__ wf_x,
    const float* __restrict__ wo_u, const float* __restrict__ wo_x,
    float* __restrict__ out) {
    __shared__ float red[4][16][129];
    int w = threadIdx.x >> 6, lane = threadIdx.x & 63;
    int c = lane & 15, q = lane >> 4;
    int b = blockIdx.x >> 6;
    int i0 = (blockIdx.x & 63) * 16;
    const unsigned short* attrow = att + ((size_t)(b * 1024 + i0 + c)) * 1024;
    const unsigned short* hTb = hT + (size_t)b * 128 * 1024;
    const float* rl0b = rl0 + b * 1024;

    f32x4 hp[8];
#pragma unroll
    for (int t = 0; t < 8; ++t) hp[t] = (f32x4){0.f, 0.f, 0.f, 0.f};

#pragma unroll
    for (int tt = 0; tt < 8; ++tt) {
        int jp = w * 8 + tt;
        int jb = jp * 32 + q * 8;
        bf16x8 eraw = *reinterpret_cast<const bf16x8*>(attrow + jb);
        float4 r0 = *reinterpret_cast<const float4*>(rl0b + jb);
        float4 r1 = *reinterpret_cast<const float4*>(rl0b + jb + 4);
        bf16x8 a;
        a[0] = (short)f2b(b2f((unsigned short)eraw[0]) * r0.x);
        a[1] = (short)f2b(b2f((unsigned short)eraw[1]) * r0.y);
        a[2] = (short)f2b(b2f((unsigned short)eraw[2]) * r0.z);
        a[3] = (short)f2b(b2f((unsigned short)eraw[3]) * r0.w);
        a[4] = (short)f2b(b2f((unsigned short)eraw[4]) * r1.x);
        a[5] = (short)f2b(b2f((unsigned short)eraw[5]) * r1.y);
        a[6] = (short)f2b(b2f((unsigned short)eraw[6]) * r1.z);
        a[7] = (short)f2b(b2f((unsigned short)eraw[7]) * r1.w);
#pragma unroll
        for (int t = 0; t < 8; ++t) {
            bf16x8 bt = *reinterpret_cast<const bf16x8*>(
                hTb + (size_t)(t * 16 + c) * 1024 + jp * 32 + q * 8);
            hp[t] = __builtin_amdgcn_mfma_f32_16x16x32_bf16(a, bt, hp[t], 0, 0, 0);
        }
    }

#pragma unroll
    for (int t = 0; t < 8; ++t)
#pragma unroll
        for (int r = 0; r < 4; ++r)
            red[w][q * 4 + r][t * 16 + c] = hp[t][r];
    __syncthreads();
    if (w != 0) return;

#pragma unroll
    for (int t = 0; t < 8; ++t)
#pragma unroll
        for (int r = 0; r < 4; ++r)
            hp[t][r] = red[0][q * 4 + r][t * 16 + c] + red[1][q * 4 + r][t * 16 + c]
                     + red[2][q * 4 + r][t * 16 + c] + red[3][q * 4 + r][t * 16 + c];

    float xv[8][4];
#pragma unroll
    for (int t = 0; t < 8; ++t)
#pragma unroll
        for (int r = 0; r < 4; ++r) {
            hp[t][r] = fmaxf(hp[t][r], 0.f);
            xv[t][r] = x[(size_t)(b * 1024 + i0 + q * 4 + r) * 128 + t * 16 + c];
        }
    float wiu[8], wix[8], wfu[8], wfx[8], wou[8], wox[8];
#pragma unroll
    for (int t = 0; t < 8; ++t) {
        wiu[t] = wi_u[t * 16 + c]; wix[t] = wi_x[t * 16 + c];
        wfu[t] = wf_u[t * 16 + c]; wfx[t] = wf_x[t * 16 + c];
        wou[t] = wo_u[t * 16 + c]; wox[t] = wo_x[t * 16 + c];
    }
#pragma unroll
    for (int r = 0; r < 4; ++r) {
        float zi = 0.f, zf = 0.f, zo = 0.f;
#pragma unroll
        for (int t = 0; t < 8; ++t) {
            zi += hp[t][r] * wiu[t] + xv[t][r] * wix[t];
            zf += hp[t][r] * wfu[t] + xv[t][r] * wfx[t];
            zo += hp[t][r] * wou[t] + xv[t][r] * wox[t];
        }
        zi += __shfl_xor(zi, 1, 64); zi += __shfl_xor(zi, 2, 64);
        zi += __shfl_xor(zi, 4, 64); zi += __shfl_xor(zi, 8, 64);
        zf += __shfl_xor(zf, 1, 64); zf += __shfl_xor(zf, 2, 64);
        zf += __shfl_xor(zf, 4, 64); zf += __shfl_xor(zf, 8, 64);
        zo += __shfl_xor(zo, 1, 64); zo += __shfl_xor(zo, 2, 64);
        zo += __shfl_xor(zo, 4, 64); zo += __shfl_xor(zo, 8, 64);
        float ic = 1.f / (1.f + __expf(-zi));
        float fc = 1.f / (1.f + __expf(-zf));
        float oc = 1.f / (1.f + __expf(-zo));
#pragma unroll
        for (int t = 0; t < 8; ++t) {
            float zz = ic * hp[t][r] + fc * xv[t][r];
            float th = 1.f - 2.f / (__expf(2.f * zz) + 1.f);
            out[(size_t)(b * 1024 + i0 + q * 4 + r) * 128 + t * 16 + c] = oc * th;
        }
    }
}

// ========== FALLBACK PATH (round-4, proven) ==========
__global__ __launch_bounds__(256) void k2_stats(
    const unsigned short* __restrict__ h, const unsigned short* __restrict__ u,
    const unsigned long long* __restrict__ maskJ, float* __restrict__ rl0) {
    int w = threadIdx.x >> 6, lane = threadIdx.x & 63;
    int c = lane & 15, q = lane >> 4;
    int b = blockIdx.x >> 6;
    int j0 = (blockIdx.x & 63) * 16;
    const unsigned short* hb = h + (size_t)b * N_ * D_;
    const unsigned short* ub = u + (size_t)b * N_ * D_;
    bf16x8 Bh[4], Bu[4];
#pragma unroll
    for (int ks = 0; ks < 4; ++ks) {
        Bh[ks] = *reinterpret_cast<const bf16x8*>(hb + (j0 + c) * 128 + ks * 32 + q * 8);
        Bu[ks] = *reinterpret_cast<const bf16x8*>(ub + (j0 + c) * 128 + ks * 32 + q * 8);
    }
    float colsum = 0.f;
    const unsigned long long* mrow = maskJ + (size_t)b * 1024 * 16 + (j0 >> 6);
    int jb = j0 & 63;
    for (int it = w; it < 64; it += 4) {
        int i0 = it * 16;
        f32x4 acc = {0.f, 0.f, 0.f, 0.f};
#pragma unroll
        for (int ks = 0; ks < 4; ++ks) {
            bf16x8 au = *reinterpret_cast<const bf16x8*>(ub + (i0 + c) * 128 + ks * 32 + q * 8);
            bf16x8 ah = *reinterpret_cast<const bf16x8*>(hb + (i0 + c) * 128 + ks * 32 + q * 8);
            acc = __builtin_amdgcn_mfma_f32_16x16x32_bf16(au, Bh[ks], acc, 0, 0, 0);
            acc = __builtin_amdgcn_mfma_f32_16x16x32_bf16(ah, Bu[ks], acc, 0, 0, 0);
        }
#pragma unroll
        for (int r = 0; r < 4; ++r) {
            int i = i0 + q * 4 + r;
            unsigned long long mword = mrow[(size_t)i * 16];
            bool m = (mword >> (jb + c)) & 1ull;
            colsum += m ? __expf(clamp60(acc[r])) : 1.0f;
        }
    }
    colsum += __shfl_xor(colsum, 16, 64);
    colsum += __shfl_xor(colsum, 32, 64);
    __shared__ float part[4][16];
    if (lane < 16) part[w][lane] = colsum;
    __syncthreads();
    if (threadIdx.x < 16) {
        float s = part[0][threadIdx.x] + part[1][threadIdx.x]
                + part[2][threadIdx.x] + part[3][threadIdx.x];
        rl0[b * 1024 + j0 + threadIdx.x] = 1.0f / s;
    }
}

__global__ __launch_bounds__(256) void k3_fused(
    const unsigned short* __restrict__ h, const unsigned short* __restrict__ uu,
    const unsigned long long* __restrict__ maskJ, const float* __restrict__ rl0,
    const unsigned short* __restrict__ hT, const float* __restrict__ x,
    const float* __restrict__ wi_u, const float* __restrict__ wi_x,
    const float* __restrict__ wf_u, const float* __restrict__ wf_x,
    const float* __restrict__ wo_u, const float* __restrict__ wo_x,
    float* __restrict__ out) {
    __shared__ float red[4][16][129];
    int w = threadIdx.x >> 6, lane = threadIdx.x & 63;
    int c = lane & 15, q = lane >> 4;
    int b = blockIdx.x >> 6;
    int i0 = (blockIdx.x & 63) * 16;
    const unsigned short* hb = h + (size_t)b * N_ * D_;
    const unsigned short* ub = uu + (size_t)b * N_ * D_;
    const unsigned short* hTb = hT + (size_t)b * 128 * 1024;
    const unsigned long long* mrowI = maskJ + (size_t)(b * 1024 + i0 + c) * 16;
    const float* rl0b = rl0 + b * 1024;
    bf16x8 Bh[4], Bu[4];
#pragma unroll
    for (int ks = 0; ks < 4; ++ks) {
        Bh[ks] = *reinterpret_cast<const bf16x8*>(hb + (i0 + c) * 128 + ks * 32 + q * 8);
        Bu[ks] = *reinterpret_cast<const bf16x8*>(ub + (i0 + c) * 128 + ks * 32 + q * 8);
    }
    f32x4 hp[8];
#pragma unroll
    for (int t = 0; t < 8; ++t) hp[t] = (f32x4){0.f, 0.f, 0.f, 0.f};
    for (int jp = w; jp < 32; jp += 4) {
        int j0 = jp * 32;
        unsigned long long mw64 = mrowI[jp >> 1];
        unsigned int mbits = (unsigned int)(mw64 >> ((jp & 1) * 32));
        unsigned int u00, u01, u10, u11;
#pragma unroll
        for (int s = 0; s < 2; ++s) {
            int js = j0 + s * 16;
            f32x4 acc = {0.f, 0.f, 0.f, 0.f};
#pragma unroll
            for (int ks = 0; ks < 4; ++ks) {
                bf16x8 au = *reinterpret_cast<const bf16x8*>(ub + (js + c) * 128 + ks * 32 + q * 8);
                bf16x8 ah = *reinterpret_cast<const bf16x8*>(hb + (js + c) * 128 + ks * 32 + q * 8);
                acc = __builtin_amdgcn_mfma_f32_16x16x32_bf16(au, Bh[ks], acc, 0, 0, 0);
                acc = __builtin_amdgcn_mfma_f32_16x16x32_bf16(ah, Bu[ks], acc, 0, 0, 0);
            }
            float4 rv = *reinterpret_cast<const float4*>(rl0b + js + q * 4);
            int bb = s * 16 + q * 4;
            float a0 = ((mbits >> (bb + 0)) & 1u) ? __expf(clamp60(acc[0])) * rv.x : 0.f;
            float a1 = ((mbits >> (bb + 1)) & 1u) ? __expf(clamp60(acc[1])) * rv.y : 0.f;
            float a2 = ((mbits >> (bb + 2)) & 1u) ? __expf(clamp60(acc[2])) * rv.z : 0.f;
            float a3 = ((mbits >> (bb + 3)) & 1u) ? __expf(clamp60(acc[3])) * rv.w : 0.f;
            unsigned int p0 = (unsigned int)f2b(a0) | ((unsigned int)f2b(a1) << 16);
            unsigned int p1 = (unsigned int)f2b(a2) | ((unsigned int)f2b(a3) << 16);
            if (s == 0) { u00 = p0; u01 = p1; } else { u10 = p0; u11 = p1; }
        }
        int la = c + 32 * (q & 1);
        int lb = la + 16;
        unsigned int x0 = __shfl((int)u00, la, 64), x1 = __shfl((int)u01, la, 64);
        unsigned int x2 = __shfl((int)u00, lb, 64), x3 = __shfl((int)u01, lb, 64);
        unsigned int y0 = __shfl((int)u10, la, 64), y1 = __shfl((int)u11, la, 64);
        unsigned int y2 = __shfl((int)u10, lb, 64), y3 = __shfl((int)u11, lb, 64);
        bool hiq = (q >> 1) != 0;
        union { unsigned int ui[4]; bf16x8 v; } att;
        att.ui[0] = hiq ? y0 : x0;
        att.ui[1] = hiq ? y1 : x1;
        att.ui[2] = hiq ? y2 : x2;
        att.ui[3] = hiq ? y3 : x3;
#pragma unroll
        for (int t = 0; t < 8; ++t) {
            bf16x8 bt = *reinterpret_cast<const bf16x8*>(
                hTb + (size_t)(t * 16 + c) * 1024 + j0 + q * 8);
            hp[t] = __builtin_amdgcn_mfma_f32_16x16x32_bf16(att.v, bt, hp[t], 0, 0, 0);
        }
    }
#pragma unroll
    for (int t = 0; t < 8; ++t)
#pragma unroll
        for (int r = 0; r < 4; ++r)
            red[w][q * 4 + r][t * 16 + c] = hp[t][r];
    __syncthreads();
    if (w != 0) return;
#pragma unroll
    for (int t = 0; t < 8; ++t)
#pragma unroll
        for (int r = 0; r < 4; ++r)
            hp[t][r] = red[0][q * 4 + r][t * 16 + c] + red[1][q * 4 + r][t * 16 + c]
                     + red[2][q * 4 + r][t * 16 + c] + red[3][q * 4 + r][t * 16 + c];
    float xv[8][4];
#pragma unroll
    for (int t = 0; t < 8; ++t)
#pragma unroll
        for (int r = 0; r < 4; ++r) {
            hp[t][r] = fmaxf(hp[t][r], 0.f);
            xv[t][r] = x[(size_t)(b * 1024 + i0 + q * 4 + r) * 128 + t * 16 + c];
        }
    float wiu[8], wix[8], wfu[8], wfx[8], wou[8], wox[8];
#pragma unroll
    for (int t = 0; t < 8; ++t) {
        wiu[t] = wi_u[t * 16 + c]; wix[t] = wi_x[t * 16 + c];
        wfu[t] = wf_u[t * 16 + c]; wfx[t] = wf_x[t * 16 + c];
        wou[t] = wo_u[t * 16 + c]; wox[t] = wo_x[t * 16 + c];
    }
#pragma unroll
    for (int r = 0; r < 4; ++r) {
        float zi = 0.f, zf = 0.f, zo = 0.f;
#pragma unroll
        for (int t = 0; t < 8; ++t) {
            zi += hp[t][r] * wiu[t] + xv[t][r] * wix[t];
            zf += hp[t][r] * wfu[t] + xv[t][r] * wfx[t];
            zo += hp[t][r] * wou[t] + xv[t][r] * wox[t];
        }
        zi += __shfl_xor(zi, 1, 64); zi += __shfl_xor(zi, 2, 64);
        zi += __shfl_xor(zi, 4, 64); zi += __shfl_xor(zi, 8, 64);
        zf += __shfl_xor(zf, 1, 64); zf += __shfl_xor(zf, 2, 64);
        zf += __shfl_xor(zf, 4, 64); zf += __shfl_xor(zf, 8, 64);
        zo += __shfl_xor(zo, 1, 64); zo += __shfl_xor(zo, 2, 64);
        zo += __shfl_xor(zo, 4, 64); zo += __shfl_xor(zo, 8, 64);
        float ic = 1.f / (1.f + __expf(-zi));
        float fc = 1.f / (1.f + __expf(-zf));
        float oc = 1.f / (1.f + __expf(-zo));
#pragma unroll
        for (int t = 0; t < 8; ++t) {
            float zz = ic * hp[t][r] + fc * xv[t][r];
            float th = 1.f - 2.f / (__expf(2.f * zz) + 1.f);
            out[(size_t)(b * 1024 + i0 + q * 4 + r) * 128 + t * 16 + c] = oc * th;
        }
    }
}

extern "C" void kernel_launch(void* const* d_in, const int* in_sizes, int n_in,
                              void* d_out, int out_size, void* d_ws, size_t ws_size,
                              hipStream_t stream) {
    const float* x    = (const float*)d_in[0];
    const float* adj  = (const float*)d_in[1];
    const float* Ww   = (const float*)d_in[2];
    const float* Wb   = (const float*)d_in[3];
    const float* A    = (const float*)d_in[4];
    const float* wi_u = (const float*)d_in[5];
    const float* wi_x = (const float*)d_in[6];
    const float* wf_u = (const float*)d_in[7];
    const float* wf_x = (const float*)d_in[8];
    const float* wo_u = (const float*)d_in[9];
    const float* wo_x = (const float*)d_in[10];
    float* out = (float*)d_out;
    char* ws = (char*)d_ws;

    if (ws_size >= (56ull << 20)) {
        // fast path layout
        unsigned short* WwB = (unsigned short*)(ws);                      // 32K
        unsigned short* W2T = (unsigned short*)(ws + (32u << 10));        // 32K
        float* wbA          = (float*)(ws + (64u << 10));                 // 512B
        float* rl0          = (float*)(ws + (128u << 10));                // 64K
        unsigned long long* maskJ = (unsigned long long*)(ws + (256u << 10)); // 2M
        float* colpart      = (float*)(ws + (4ull << 20));                // 2M
        unsigned short* h   = (unsigned short*)(ws + (8ull << 20));       // 4M
        unsigned short* u   = (unsigned short*)(ws + (12ull << 20));      // 4M
        unsigned short* hT  = (unsigned short*)(ws + (16ull << 20));      // 4M
        unsigned short* att = (unsigned short*)(ws + (20ull << 20));      // 32M

        k0_w2t<<<64, 256, 0, stream>>>(Ww, Wb, A, WwB, W2T, wbA);
        kmask<<<16384, 256, 0, stream>>>(adj, maskJ);
        k1_hu<<<1024, 256, 0, stream>>>(x, WwB, Wb, W2T, wbA, h, u, hT);
        k2_scores<<<512, 256, 0, stream>>>(h, u, maskJ, att, colpart);
        k2b_recip<<<64, 256, 0, stream>>>(colpart, rl0);
        k3_gemm<<<1024, 256, 0, stream>>>(att, rl0, hT, x,
                                          wi_u, wi_x, wf_u, wf_x, wo_u, wo_x, out);
    } else {
        // fallback: round-4 layout + kernels
        unsigned short* WwB = (unsigned short*)(ws);
        unsigned short* W2T = (unsigned short*)(ws + (32u << 10));
        float* wbA          = (float*)(ws + (64u << 10));
        float* rl0          = (float*)(ws + (128u << 10));
        unsigned short* h   = (unsigned short*)(ws + (1u << 20));
        unsigned short* u   = (unsigned short*)(ws + (5u << 20));
        unsigned short* hT  = (unsigned short*)(ws + (9u << 20));
        unsigned long long* maskJ = (unsigned long long*)(ws + (13u << 20));

        k0_w2t<<<64, 256, 0, stream>>>(Ww, Wb, A, WwB, W2T, wbA);
        kmask<<<16384, 256, 0, stream>>>(adj, maskJ);
        k1_hu<<<1024, 256, 0, stream>>>(x, WwB, Wb, W2T, wbA, h, u, hT);
        k2_stats<<<1024, 256, 0, stream>>>(h, u, maskJ, rl0);
        k3_fused<<<1024, 256, 0, stream>>>(h, u, maskJ, rl0, hT, x,
                                           wi_u, wi_x, wf_u, wf_x, wo_u, wo_x, out);
    }
}

// Round 10
// 223.627 us; speedup vs baseline: 1.2213x; 1.0056x over previous
//
#include <hip/hip_runtime.h>
#include <hip/hip_cooperative_groups.h>

namespace cg = cooperative_groups;

// GAT_gate: B=16, N=1024, D=128. FP32 I/O; bf16 MFMA internally, fp32 accum.
//
// COOP path (one dispatch, grid.sync between phases) -- kills ~100us of
// inter-dispatch overhead measured in rounds 5-9 (kernel sum 125us vs 225 total):
//  P0: weight fold + colsum zero + adj->bitmask (loads batched BEFORE ballots --
//      r8 lesson: ballot interleaved with loads serializes MLP, 60us vs 14us)
//  P1: h = x@Ww^T+Wb ; u = x@W2T^T+wbA -> h,u bf16; hT bf16 [b][d][n]
//  P2: scores: unit = 32 rows x 512 cols (1024 units -> 4 blocks/CU, 2x r9 TLP);
//      att = mask?exp(e):0 bf16; colsum via atomicAdd (disjoint j per unit class)
//  P3: colsum -> 1/colsum in place
//  P4: h' = relu((att*rl0)@h) vs hT + LSTM-gate epilogue
// Fallback: round-9 6-dispatch path (proven 225us).

#define B_ 16
#define N_ 1024
#define D_ 128

typedef __attribute__((ext_vector_type(8))) short bf16x8;
typedef __attribute__((ext_vector_type(4))) float f32x4;

__device__ __forceinline__ float b2f(unsigned short u) {
    union { unsigned int i; float f; } v; v.i = ((unsigned int)u) << 16; return v.f;
}
__device__ __forceinline__ unsigned short f2b(float f) {
    union { float f; unsigned int i; } v; v.f = f;
    unsigned int x = v.i;
    return (unsigned short)((x + 0x7fffu + ((x >> 16) & 1u)) >> 16);
}
__device__ __forceinline__ float clamp60(float v) {
    return fminf(fmaxf(v, -60.f), 60.f);
}
__device__ __forceinline__ bf16x8 load8f(const float* p) {
    float4 a = *reinterpret_cast<const float4*>(p);
    float4 b = *reinterpret_cast<const float4*>(p + 4);
    bf16x8 v;
    v[0] = (short)f2b(a.x); v[1] = (short)f2b(a.y);
    v[2] = (short)f2b(a.z); v[3] = (short)f2b(a.w);
    v[4] = (short)f2b(b.x); v[5] = (short)f2b(b.y);
    v[6] = (short)f2b(b.z); v[7] = (short)f2b(b.w);
    return v;
}

struct MegaArgs {
    const float *x, *adj, *Ww, *Wb, *A;
    const float *wi_u, *wi_x, *wf_u, *wf_x, *wo_u, *wo_x;
    float* out;
    unsigned short *WwB, *W2T;
    float *wbA, *colsum;
    unsigned long long* maskJ;
    unsigned short *h, *u, *hT, *att;
};

__global__ __launch_bounds__(256) void mega(MegaArgs a) {
    cg::grid_group gg = cg::this_grid();
    __shared__ __align__(16) unsigned char smem[33024];
    int tid = threadIdx.x;
    int w = tid >> 6, lane = tid & 63;
    int c = lane & 15, q = lane >> 4;

    // ================= P0: weight fold + colsum zero + kmask =================
    for (int ub = blockIdx.x; ub < 64; ub += gridDim.x) {
        int t = ub * 256 + tid;
        int l = t >> 7, f = t & 127;
        float acc = 0.f;
        for (int d = 0; d < 128; ++d)
            acc += a.A[d * 128 + l] * a.Ww[d * 128 + f];
        a.W2T[l * 128 + f] = f2b(acc);
        a.WwB[t] = f2b(a.Ww[t]);
        a.colsum[t] = 0.f;
        if (ub == 0 && tid < 128) {
            float s = 0.f;
            for (int d = 0; d < 128; ++d) s += a.Wb[d] * a.A[d * 128 + tid];
            a.wbA[tid] = s;
        }
    }
    // kmask: 16M elems, 4096 elems per block-iteration (16 loads/lane batched,
    // THEN 16 ballots -- keeps memory-level parallelism)
    for (int ub = blockIdx.x; ub < 4096; ub += gridDim.x) {
        size_t base = ((size_t)ub * 4 + w) * 1024;
        float v[16];
#pragma unroll
        for (int k = 0; k < 16; ++k) v[k] = a.adj[base + (size_t)k * 64 + lane];
        unsigned long long m[16];
#pragma unroll
        for (int k = 0; k < 16; ++k) m[k] = __ballot(v[k] > 0.f);
        unsigned long long mv = 0;
#pragma unroll
        for (int k = 0; k < 16; ++k) if (lane == k) mv = m[k];
        if (lane < 16) a.maskJ[(base >> 6) + lane] = mv;
    }
    gg.sync();

    // ================= P1: h, u, hT =================
    {
        auto lds1 = reinterpret_cast<unsigned short(*)[128]>(smem);
        for (int blk = blockIdx.x; blk < 1024; blk += gridDim.x) {
            int rowbase = blk * 16;
            int b = rowbase >> 10;
            int n0 = rowbase & 1023;
            bf16x8 xa[4];
            const float* xrow = a.x + (size_t)(rowbase + c) * 128;
#pragma unroll
            for (int ks = 0; ks < 4; ++ks)
                xa[ks] = load8f(xrow + ks * 32 + q * 8);
#pragma unroll
            for (int tt = 0; tt < 2; ++tt) {
                int t = w * 2 + tt;
                f32x4 acch = {0.f, 0.f, 0.f, 0.f};
                f32x4 accu = {0.f, 0.f, 0.f, 0.f};
                const unsigned short* wwrow = a.WwB + (t * 16 + c) * 128;
                const unsigned short* w2row = a.W2T + (t * 16 + c) * 128;
#pragma unroll
                for (int ks = 0; ks < 4; ++ks) {
                    bf16x8 bw = *reinterpret_cast<const bf16x8*>(wwrow + ks * 32 + q * 8);
                    bf16x8 b2 = *reinterpret_cast<const bf16x8*>(w2row + ks * 32 + q * 8);
                    acch = __builtin_amdgcn_mfma_f32_16x16x32_bf16(xa[ks], bw, acch, 0, 0, 0);
                    accu = __builtin_amdgcn_mfma_f32_16x16x32_bf16(xa[ks], b2, accu, 0, 0, 0);
                }
                float wb = a.Wb[t * 16 + c];
                float ub2 = a.wbA[t * 16 + c];
#pragma unroll
                for (int r = 0; r < 4; ++r) {
                    int row = rowbase + q * 4 + r;
                    unsigned short hv = f2b(acch[r] + wb);
                    unsigned short uv = f2b(accu[r] + ub2);
                    a.h[(size_t)row * 128 + t * 16 + c] = hv;
                    a.u[(size_t)row * 128 + t * 16 + c] = uv;
                    lds1[q * 4 + r][t * 16 + c] = hv;
                }
            }
            __syncthreads();
            if (tid < 128) {
                int d = tid;
                unsigned int p[8];
#pragma unroll
                for (int k = 0; k < 8; ++k) {
                    unsigned int v0 = lds1[2 * k][d], v1 = lds1[2 * k + 1][d];
                    p[k] = v0 | (v1 << 16);
                }
                size_t basehT = ((size_t)(b * 128 + d)) * 1024 + n0;
                uint4* dst = reinterpret_cast<uint4*>(a.hT + basehT);
                dst[0] = make_uint4(p[0], p[1], p[2], p[3]);
                dst[1] = make_uint4(p[4], p[5], p[6], p[7]);
            }
            __syncthreads();
        }
    }
    gg.sync();

    // ================= P2: scores (32 rows x 512 cols per unit) =================
    {
        auto lmask = reinterpret_cast<unsigned long long(*)[8]>(smem);
        for (int blk = blockIdx.x; blk < 1024; blk += gridDim.x) {
            int b = blk >> 6, rem = blk & 63;
            int iblk = rem >> 1, jh = rem & 1;
            int i0 = iblk * 32, jbase = jh * 512;
            const unsigned short* hb = a.h + (size_t)b * N_ * D_;
            const unsigned short* ub2 = a.u + (size_t)b * N_ * D_;

            lmask[tid >> 3][tid & 7] =
                a.maskJ[(size_t)(b * 1024 + i0 + (tid >> 3)) * 16 + (jbase >> 6) + (tid & 7)];
            __syncthreads();

            bf16x8 Au0[4], Ah0[4], Au1[4], Ah1[4];
#pragma unroll
            for (int ks = 0; ks < 4; ++ks) {
                Au0[ks] = *reinterpret_cast<const bf16x8*>(ub2 + (i0 + c) * 128 + ks * 32 + q * 8);
                Ah0[ks] = *reinterpret_cast<const bf16x8*>(hb + (i0 + c) * 128 + ks * 32 + q * 8);
                Au1[ks] = *reinterpret_cast<const bf16x8*>(ub2 + (i0 + 16 + c) * 128 + ks * 32 + q * 8);
                Ah1[ks] = *reinterpret_cast<const bf16x8*>(hb + (i0 + 16 + c) * 128 + ks * 32 + q * 8);
            }
            unsigned short* attrow = a.att + ((size_t)(b * 1024 + i0)) * 1024;
            float* csb = a.colsum + b * 1024;

            int lt0 = w * 8;
#pragma unroll
            for (int t = 0; t < 8; ++t) {
                int lt = lt0 + t;
                int j0 = jbase + lt * 16;
                bf16x8 Bh[4], Bu[4];
#pragma unroll
                for (int ks = 0; ks < 4; ++ks) {
                    Bh[ks] = *reinterpret_cast<const bf16x8*>(hb + (j0 + c) * 128 + ks * 32 + q * 8);
                    Bu[ks] = *reinterpret_cast<const bf16x8*>(ub2 + (j0 + c) * 128 + ks * 32 + q * 8);
                }
                f32x4 a00 = {0.f, 0.f, 0.f, 0.f};
                f32x4 a01 = {0.f, 0.f, 0.f, 0.f};
                f32x4 a10 = {0.f, 0.f, 0.f, 0.f};
                f32x4 a11 = {0.f, 0.f, 0.f, 0.f};
#pragma unroll
                for (int ks = 0; ks < 4; ++ks) {
                    a00 = __builtin_amdgcn_mfma_f32_16x16x32_bf16(Au0[ks], Bh[ks], a00, 0, 0, 0);
                    a01 = __builtin_amdgcn_mfma_f32_16x16x32_bf16(Ah0[ks], Bu[ks], a01, 0, 0, 0);
                    a10 = __builtin_amdgcn_mfma_f32_16x16x32_bf16(Au1[ks], Bh[ks], a10, 0, 0, 0);
                    a11 = __builtin_amdgcn_mfma_f32_16x16x32_bf16(Ah1[ks], Bu[ks], a11, 0, 0, 0);
                }
                int wd = lt >> 2, sh = (lt & 3) * 16;
                float colp = 0.f;
#pragma unroll
                for (int r = 0; r < 4; ++r) {
                    float e0 = a00[r] + a01[r];
                    float e1 = a10[r] + a11[r];
                    bool m0 = (lmask[q * 4 + r][wd] >> (sh + c)) & 1ull;
                    bool m1 = (lmask[16 + q * 4 + r][wd] >> (sh + c)) & 1ull;
                    float ex0 = m0 ? __expf(clamp60(e0)) : 0.f;
                    float ex1 = m1 ? __expf(clamp60(e1)) : 0.f;
                    colp += (m0 ? ex0 : 1.0f) + (m1 ? ex1 : 1.0f);
                    attrow[(size_t)(q * 4 + r) * 1024 + j0 + c] = f2b(ex0);
                    attrow[(size_t)(16 + q * 4 + r) * 1024 + j0 + c] = f2b(ex1);
                }
                colp += __shfl_xor(colp, 16, 64);
                colp += __shfl_xor(colp, 32, 64);
                if (q == 0) atomicAdd(&csb[j0 + c], colp);
            }
            __syncthreads();
        }
    }
    gg.sync();

    // ================= P3: colsum -> reciprocal =================
    for (int g2 = blockIdx.x * 256 + tid; g2 < 16384; g2 += gridDim.x * 256)
        a.colsum[g2] = 1.0f / a.colsum[g2];
    gg.sync();

    // ================= P4: aggregation + gates =================
    {
        auto red = reinterpret_cast<float(*)[16][129]>(smem);
        for (int blk = blockIdx.x; blk < 1024; blk += gridDim.x) {
            int b = blk >> 6;
            int i0 = (blk & 63) * 16;
            const unsigned short* attrow = a.att + ((size_t)(b * 1024 + i0 + c)) * 1024;
            const unsigned short* hTb = a.hT + (size_t)b * 128 * 1024;
            const float* rl0b = a.colsum + b * 1024;

            f32x4 hp[8];
#pragma unroll
            for (int t = 0; t < 8; ++t) hp[t] = (f32x4){0.f, 0.f, 0.f, 0.f};

#pragma unroll
            for (int tt = 0; tt < 8; ++tt) {
                int jp = w * 8 + tt;
                int jb = jp * 32 + q * 8;
                bf16x8 eraw = *reinterpret_cast<const bf16x8*>(attrow + jb);
                float4 r0 = *reinterpret_cast<const float4*>(rl0b + jb);
                float4 r1 = *reinterpret_cast<const float4*>(rl0b + jb + 4);
                bf16x8 av;
                av[0] = (short)f2b(b2f((unsigned short)eraw[0]) * r0.x);
                av[1] = (short)f2b(b2f((unsigned short)eraw[1]) * r0.y);
                av[2] = (short)f2b(b2f((unsigned short)eraw[2]) * r0.z);
                av[3] = (short)f2b(b2f((unsigned short)eraw[3]) * r0.w);
                av[4] = (short)f2b(b2f((unsigned short)eraw[4]) * r1.x);
                av[5] = (short)f2b(b2f((unsigned short)eraw[5]) * r1.y);
                av[6] = (short)f2b(b2f((unsigned short)eraw[6]) * r1.z);
                av[7] = (short)f2b(b2f((unsigned short)eraw[7]) * r1.w);
#pragma unroll
                for (int t = 0; t < 8; ++t) {
                    bf16x8 bt = *reinterpret_cast<const bf16x8*>(
                        hTb + (size_t)(t * 16 + c) * 1024 + jp * 32 + q * 8);
                    hp[t] = __builtin_amdgcn_mfma_f32_16x16x32_bf16(av, bt, hp[t], 0, 0, 0);
                }
            }

#pragma unroll
            for (int t = 0; t < 8; ++t)
#pragma unroll
                for (int r = 0; r < 4; ++r)
                    red[w][q * 4 + r][t * 16 + c] = hp[t][r];
            __syncthreads();
            if (w == 0) {
#pragma unroll
                for (int t = 0; t < 8; ++t)
#pragma unroll
                    for (int r = 0; r < 4; ++r)
                        hp[t][r] = red[0][q * 4 + r][t * 16 + c] + red[1][q * 4 + r][t * 16 + c]
                                 + red[2][q * 4 + r][t * 16 + c] + red[3][q * 4 + r][t * 16 + c];
                float xv[8][4];
#pragma unroll
                for (int t = 0; t < 8; ++t)
#pragma unroll
                    for (int r = 0; r < 4; ++r) {
                        hp[t][r] = fmaxf(hp[t][r], 0.f);
                        xv[t][r] = a.x[(size_t)(b * 1024 + i0 + q * 4 + r) * 128 + t * 16 + c];
                    }
                float wiu[8], wix[8], wfu[8], wfx[8], wou[8], wox[8];
#pragma unroll
                for (int t = 0; t < 8; ++t) {
                    wiu[t] = a.wi_u[t * 16 + c]; wix[t] = a.wi_x[t * 16 + c];
                    wfu[t] = a.wf_u[t * 16 + c]; wfx[t] = a.wf_x[t * 16 + c];
                    wou[t] = a.wo_u[t * 16 + c]; wox[t] = a.wo_x[t * 16 + c];
                }
#pragma unroll
                for (int r = 0; r < 4; ++r) {
                    float zi = 0.f, zf = 0.f, zo = 0.f;
#pragma unroll
                    for (int t = 0; t < 8; ++t) {
                        zi += hp[t][r] * wiu[t] + xv[t][r] * wix[t];
                        zf += hp[t][r] * wfu[t] + xv[t][r] * wfx[t];
                        zo += hp[t][r] * wou[t] + xv[t][r] * wox[t];
                    }
                    zi += __shfl_xor(zi, 1, 64); zi += __shfl_xor(zi, 2, 64);
                    zi += __shfl_xor(zi, 4, 64); zi += __shfl_xor(zi, 8, 64);
                    zf += __shfl_xor(zf, 1, 64); zf += __shfl_xor(zf, 2, 64);
                    zf += __shfl_xor(zf, 4, 64); zf += __shfl_xor(zf, 8, 64);
                    zo += __shfl_xor(zo, 1, 64); zo += __shfl_xor(zo, 2, 64);
                    zo += __shfl_xor(zo, 4, 64); zo += __shfl_xor(zo, 8, 64);
                    float ic = 1.f / (1.f + __expf(-zi));
                    float fc = 1.f / (1.f + __expf(-zf));
                    float oc = 1.f / (1.f + __expf(-zo));
#pragma unroll
                    for (int t = 0; t < 8; ++t) {
                        float zz = ic * hp[t][r] + fc * xv[t][r];
                        float th = 1.f - 2.f / (__expf(2.f * zz) + 1.f);
                        a.out[(size_t)(b * 1024 + i0 + q * 4 + r) * 128 + t * 16 + c] = oc * th;
                    }
                }
            }
            __syncthreads();
        }
    }
}

// ========== FALLBACK PATH (round-9, proven 225us) ==========
__global__ __launch_bounds__(256) void k0_w2t(
    const float* __restrict__ Ww, const float* __restrict__ Wb,
    const float* __restrict__ A, unsigned short* __restrict__ WwB,
    unsigned short* __restrict__ W2T, float* __restrict__ wbA) {
    int t = blockIdx.x * 256 + threadIdx.x;
    int l = t >> 7, f = t & 127;
    float acc = 0.f;
    for (int d = 0; d < 128; ++d)
        acc += A[d * 128 + l] * Ww[d * 128 + f];
    W2T[l * 128 + f] = f2b(acc);
    WwB[t] = f2b(Ww[t]);
    if (blockIdx.x == 0 && threadIdx.x < 128) {
        float s = 0.f;
        for (int d = 0; d < 128; ++d) s += Wb[d] * A[d * 128 + threadIdx.x];
        wbA[threadIdx.x] = s;
    }
}

__global__ __launch_bounds__(256) void kmask(
    const float* __restrict__ adj, unsigned long long* __restrict__ maskJ) {
    int w = threadIdx.x >> 6, lane = threadIdx.x & 63;
    size_t base = ((size_t)blockIdx.x * 4 + w) * 256;
    unsigned long long w0 = __ballot(adj[base + 0 * 64 + lane] > 0.f);
    unsigned long long w1 = __ballot(adj[base + 1 * 64 + lane] > 0.f);
    unsigned long long w2 = __ballot(adj[base + 2 * 64 + lane] > 0.f);
    unsigned long long w3 = __ballot(adj[base + 3 * 64 + lane] > 0.f);
    unsigned long long o = lane == 0 ? w0 : lane == 1 ? w1 : lane == 2 ? w2 : w3;
    if (lane < 4) maskJ[(base >> 6) + lane] = o;
}

__global__ __launch_bounds__(256) void k1_hu(
    const float* __restrict__ x, const unsigned short* __restrict__ WwB,
    const float* __restrict__ Wb, const unsigned short* __restrict__ W2T,
    const float* __restrict__ wbA,
    unsigned short* __restrict__ h, unsigned short* __restrict__ u,
    unsigned short* __restrict__ hT) {
    __shared__ unsigned short lds[16][128];
    int w = threadIdx.x >> 6, lane = threadIdx.x & 63;
    int c = lane & 15, q = lane >> 4;
    int rowbase = blockIdx.x * 16;
    int b = rowbase >> 10;
    int n0 = rowbase & 1023;
    bf16x8 xa[4];
    const float* xrow = x + (size_t)(rowbase + c) * 128;
#pragma unroll
    for (int ks = 0; ks < 4; ++ks)
        xa[ks] = load8f(xrow + ks * 32 + q * 8);
#pragma unroll
    for (int tt = 0; tt < 2; ++tt) {
        int t = w * 2 + tt;
        f32x4 acch = {0.f, 0.f, 0.f, 0.f};
        f32x4 accu = {0.f, 0.f, 0.f, 0.f};
        const unsigned short* wwrow = WwB + (t * 16 + c) * 128;
        const unsigned short* w2row = W2T + (t * 16 + c) * 128;
#pragma unroll
        for (int ks = 0; ks < 4; ++ks) {
            bf16x8 bw = *reinterpret_cast<const bf16x8*>(wwrow + ks * 32 + q * 8);
            bf16x8 b2 = *reinterpret_cast<const bf16x8*>(w2row + ks * 32 + q * 8);
            acch = __builtin_amdgcn_mfma_f32_16x16x32_bf16(xa[ks], bw, acch, 0, 0, 0);
            accu = __builtin_amdgcn_mfma_f32_16x16x32_bf16(xa[ks], b2, accu, 0, 0, 0);
        }
        float wb = Wb[t * 16 + c];
        float ub = wbA[t * 16 + c];
#pragma unroll
        for (int r = 0; r < 4; ++r) {
            int row = rowbase + q * 4 + r;
            unsigned short hv = f2b(acch[r] + wb);
            unsigned short uv = f2b(accu[r] + ub);
            h[(size_t)row * 128 + t * 16 + c] = hv;
            u[(size_t)row * 128 + t * 16 + c] = uv;
            lds[q * 4 + r][t * 16 + c] = hv;
        }
    }
    __syncthreads();
    int tid = threadIdx.x;
    if (tid < 128) {
        int d = tid;
        unsigned int p[8];
#pragma unroll
        for (int k = 0; k < 8; ++k) {
            unsigned int v0 = lds[2 * k][d], v1 = lds[2 * k + 1][d];
            p[k] = v0 | (v1 << 16);
        }
        size_t basehT = ((size_t)(b * 128 + d)) * 1024 + n0;
        uint4* dst = reinterpret_cast<uint4*>(hT + basehT);
        dst[0] = make_uint4(p[0], p[1], p[2], p[3]);
        dst[1] = make_uint4(p[4], p[5], p[6], p[7]);
    }
}

__global__ __launch_bounds__(256) void k2_scores(
    const unsigned short* __restrict__ h, const unsigned short* __restrict__ u,
    const unsigned long long* __restrict__ maskJ,
    unsigned short* __restrict__ att, float* __restrict__ colpart) {
    __shared__ unsigned long long lmask[32][16];
    int w = threadIdx.x >> 6, lane = threadIdx.x & 63;
    int c = lane & 15, q = lane >> 4;
    int b = blockIdx.x >> 5;
    int iblk = blockIdx.x & 31;
    int i0 = iblk * 32;
    const unsigned short* hb = h + (size_t)b * N_ * D_;
    const unsigned short* ub = u + (size_t)b * N_ * D_;
    {
        int tid = threadIdx.x;
        lmask[tid >> 4][tid & 15] =
            maskJ[(size_t)(b * 1024 + i0 + (tid >> 4)) * 16 + (tid & 15)];
        lmask[16 + (tid >> 4)][tid & 15] =
            maskJ[(size_t)(b * 1024 + i0 + 16 + (tid >> 4)) * 16 + (tid & 15)];
    }
    __syncthreads();
    bf16x8 Au0[4], Ah0[4], Au1[4], Ah1[4];
#pragma unroll
    for (int ks = 0; ks < 4; ++ks) {
        Au0[ks] = *reinterpret_cast<const bf16x8*>(ub + (i0 + c) * 128 + ks * 32 + q * 8);
        Ah0[ks] = *reinterpret_cast<const bf16x8*>(hb + (i0 + c) * 128 + ks * 32 + q * 8);
        Au1[ks] = *reinterpret_cast<const bf16x8*>(ub + (i0 + 16 + c) * 128 + ks * 32 + q * 8);
        Ah1[ks] = *reinterpret_cast<const bf16x8*>(hb + (i0 + 16 + c) * 128 + ks * 32 + q * 8);
    }
    unsigned short* attrow = att + ((size_t)(b * 1024 + i0)) * 1024;
    float* cprow = colpart + ((size_t)(b * 32 + iblk)) * 1024;
    int jt0 = w * 16;
#pragma unroll
    for (int t = 0; t < 16; ++t) {
        int jt = jt0 + t, j0 = jt * 16;
        bf16x8 Bh[4], Bu[4];
#pragma unroll
        for (int ks = 0; ks < 4; ++ks) {
            Bh[ks] = *reinterpret_cast<const bf16x8*>(hb + (j0 + c) * 128 + ks * 32 + q * 8);
            Bu[ks] = *reinterpret_cast<const bf16x8*>(ub + (j0 + c) * 128 + ks * 32 + q * 8);
        }
        f32x4 a00 = {0.f, 0.f, 0.f, 0.f};
        f32x4 a01 = {0.f, 0.f, 0.f, 0.f};
        f32x4 a10 = {0.f, 0.f, 0.f, 0.f};
        f32x4 a11 = {0.f, 0.f, 0.f, 0.f};
#pragma unroll
        for (int ks = 0; ks < 4; ++ks) {
            a00 = __builtin_amdgcn_mfma_f32_16x16x32_bf16(Au0[ks], Bh[ks], a00, 0, 0, 0);
            a01 = __builtin_amdgcn_mfma_f32_16x16x32_bf16(Ah0[ks], Bu[ks], a01, 0, 0, 0);
            a10 = __builtin_amdgcn_mfma_f32_16x16x32_bf16(Au1[ks], Bh[ks], a10, 0, 0, 0);
            a11 = __builtin_amdgcn_mfma_f32_16x16x32_bf16(Ah1[ks], Bu[ks], a11, 0, 0, 0);
        }
        int wd = jt >> 2, sh = (jt & 3) * 16;
        float colp = 0.f;
#pragma unroll
        for (int r = 0; r < 4; ++r) {
            float e0 = a00[r] + a01[r];
            float e1 = a10[r] + a11[r];
            bool m0 = (lmask[q * 4 + r][wd] >> (sh + c)) & 1ull;
            bool m1 = (lmask[16 + q * 4 + r][wd] >> (sh + c)) & 1ull;
            float ex0 = m0 ? __expf(clamp60(e0)) : 0.f;
            float ex1 = m1 ? __expf(clamp60(e1)) : 0.f;
            colp += (m0 ? ex0 : 1.0f) + (m1 ? ex1 : 1.0f);
            attrow[(size_t)(q * 4 + r) * 1024 + j0 + c] = f2b(ex0);
            attrow[(size_t)(16 + q * 4 + r) * 1024 + j0 + c] = f2b(ex1);
        }
        colp += __shfl_xor(colp, 16, 64);
        colp += __shfl_xor(colp, 32, 64);
        if (q == 0) cprow[j0 + c] = colp;
    }
}

__global__ __launch_bounds__(256) void k2b_recip(
    const float* __restrict__ colpart, float* __restrict__ rl0) {
    int g = blockIdx.x * 256 + threadIdx.x;
    int b = g >> 10, j = g & 1023;
    float s = 0.f;
    const float* p = colpart + (size_t)b * 32 * 1024 + j;
    for (int ib = 0; ib < 32; ++ib) s += p[(size_t)ib * 1024];
    rl0[g] = 1.0f / s;
}

__global__ __launch_bounds__(256) void k3_gemm(
    const unsigned short* __restrict__ att, const float* __restrict__ rl0,
    const unsigned short* __restrict__ hT, const float* __restrict__ x,
    const float* __restrict__ wi_u, const float* __restrict__ wi_x,
    const float* __restrict__ wf_u, const float* __restrict__ wf_x,
    const float* __restrict__ wo_u, const float* __restrict__ wo_x,
    float* __restrict__ out) {
    __shared__ float red[4][16][129];
    int w = threadIdx.x >> 6, lane = threadIdx.x & 63;
    int c = lane & 15, q = lane >> 4;
    int b = blockIdx.x >> 6;
    int i0 = (blockIdx.x & 63) * 16;
    const unsigned short* attrow = att + ((size_t)(b * 1024 + i0 + c)) * 1024;
    const unsigned short* hTb = hT + (size_t)b * 128 * 1024;
    const float* rl0b = rl0 + b * 1024;
    f32x4 hp[8];
#pragma unroll
    for (int t = 0; t < 8; ++t) hp[t] = (f32x4){0.f, 0.f, 0.f, 0.f};
#pragma unroll
    for (int tt = 0; tt < 8; ++tt) {
        int jp = w * 8 + tt;
        int jb = jp * 32 + q * 8;
        bf16x8 eraw = *reinterpret_cast<const bf16x8*>(attrow + jb);
        float4 r0 = *reinterpret_cast<const float4*>(rl0b + jb);
        float4 r1 = *reinterpret_cast<const float4*>(rl0b + jb + 4);
        bf16x8 av;
        av[0] = (short)f2b(b2f((unsigned short)eraw[0]) * r0.x);
        av[1] = (short)f2b(b2f((unsigned short)eraw[1]) * r0.y);
        av[2] = (short)f2b(b2f((unsigned short)eraw[2]) * r0.z);
        av[3] = (short)f2b(b2f((unsigned short)eraw[3]) * r0.w);
        av[4] = (short)f2b(b2f((unsigned short)eraw[4]) * r1.x);
        av[5] = (short)f2b(b2f((unsigned short)eraw[5]) * r1.y);
        av[6] = (short)f2b(b2f((unsigned short)eraw[6]) * r1.z);
        av[7] = (short)f2b(b2f((unsigned short)eraw[7]) * r1.w);
#pragma unroll
        for (int t = 0; t < 8; ++t) {
            bf16x8 bt = *reinterpret_cast<const bf16x8*>(
                hTb + (size_t)(t * 16 + c) * 1024 + jp * 32 + q * 8);
            hp[t] = __builtin_amdgcn_mfma_f32_16x16x32_bf16(av, bt, hp[t], 0, 0, 0);
        }
    }
#pragma unroll
    for (int t = 0; t < 8; ++t)
#pragma unroll
        for (int r = 0; r < 4; ++r)
            red[w][q * 4 + r][t * 16 + c] = hp[t][r];
    __syncthreads();
    if (w != 0) return;
#pragma unroll
    for (int t = 0; t < 8; ++t)
#pragma unroll
        for (int r = 0; r < 4; ++r)
            hp[t][r] = red[0][q * 4 + r][t * 16 + c] + red[1][q * 4 + r][t * 16 + c]
                     + red[2][q * 4 + r][t * 16 + c] + red[3][q * 4 + r][t * 16 + c];
    float xv[8][4];
#pragma unroll
    for (int t = 0; t < 8; ++t)
#pragma unroll
        for (int r = 0; r < 4; ++r) {
            hp[t][r] = fmaxf(hp[t][r], 0.f);
            xv[t][r] = x[(size_t)(b * 1024 + i0 + q * 4 + r) * 128 + t * 16 + c];
        }
    float wiu[8], wix[8], wfu[8], wfx[8], wou[8], wox[8];
#pragma unroll
    for (int t = 0; t < 8; ++t) {
        wiu[t] = wi_u[t * 16 + c]; wix[t] = wi_x[t * 16 + c];
        wfu[t] = wf_u[t * 16 + c]; wfx[t] = wf_x[t * 16 + c];
        wou[t] = wo_u[t * 16 + c]; wox[t] = wo_x[t * 16 + c];
    }
#pragma unroll
    for (int r = 0; r < 4; ++r) {
        float zi = 0.f, zf = 0.f, zo = 0.f;
#pragma unroll
        for (int t = 0; t < 8; ++t) {
            zi += hp[t][r] * wiu[t] + xv[t][r] * wix[t];
            zf += hp[t][r] * wfu[t] + xv[t][r] * wfx[t];
            zo += hp[t][r] * wou[t] + xv[t][r] * wox[t];
        }
        zi += __shfl_xor(zi, 1, 64); zi += __shfl_xor(zi, 2, 64);
        zi += __shfl_xor(zi, 4, 64); zi += __shfl_xor(zi, 8, 64);
        zf += __shfl_xor(zf, 1, 64); zf += __shfl_xor(zf, 2, 64);
        zf += __shfl_xor(zf, 4, 64); zf += __shfl_xor(zf, 8, 64);
        zo += __shfl_xor(zo, 1, 64); zo += __shfl_xor(zo, 2, 64);
        zo += __shfl_xor(zo, 4, 64); zo += __shfl_xor(zo, 8, 64);
        float ic = 1.f / (1.f + __expf(-zi));
        float fc = 1.f / (1.f + __expf(-zf));
        float oc = 1.f / (1.f + __expf(-zo));
#pragma unroll
        for (int t = 0; t < 8; ++t) {
            float zz = ic * hp[t][r] + fc * xv[t][r];
            float th = 1.f - 2.f / (__expf(2.f * zz) + 1.f);
            out[(size_t)(b * 1024 + i0 + q * 4 + r) * 128 + t * 16 + c] = oc * th;
        }
    }
}

extern "C" void kernel_launch(void* const* d_in, const int* in_sizes, int n_in,
                              void* d_out, int out_size, void* d_ws, size_t ws_size,
                              hipStream_t stream) {
    const float* x    = (const float*)d_in[0];
    const float* adj  = (const float*)d_in[1];
    const float* Ww   = (const float*)d_in[2];
    const float* Wb   = (const float*)d_in[3];
    const float* A    = (const float*)d_in[4];
    const float* wi_u = (const float*)d_in[5];
    const float* wi_x = (const float*)d_in[6];
    const float* wf_u = (const float*)d_in[7];
    const float* wf_x = (const float*)d_in[8];
    const float* wo_u = (const float*)d_in[9];
    const float* wo_x = (const float*)d_in[10];
    float* out = (float*)d_out;
    char* ws = (char*)d_ws;

    // shared ws layout (fast + fallback compatible)
    unsigned short* WwB = (unsigned short*)(ws);                      // 32K
    unsigned short* W2T = (unsigned short*)(ws + (32u << 10));        // 32K
    float* wbA          = (float*)(ws + (64u << 10));                 // 512B
    float* rl0          = (float*)(ws + (128u << 10));                // 64K (colsum)
    unsigned long long* maskJ = (unsigned long long*)(ws + (256u << 10)); // 2M
    float* colpart      = (float*)(ws + (4ull << 20));                // 2M (fallback)
    unsigned short* h   = (unsigned short*)(ws + (8ull << 20));       // 4M
    unsigned short* u   = (unsigned short*)(ws + (12ull << 20));      // 4M
    unsigned short* hT  = (unsigned short*)(ws + (16ull << 20));      // 4M
    unsigned short* att = (unsigned short*)(ws + (20ull << 20));      // 32M

    // one-time coop capability probe (host-side, deterministic; GPU work
    // identical every call). First call is uncaptured per harness contract.
    static int coopGrid = -1;
    if (coopGrid < 0) {
        coopGrid = 0;
        hipDeviceProp_t prop;
        if (hipGetDeviceProperties(&prop, 0) == hipSuccess && prop.cooperativeLaunch) {
            int maxB = 0;
            if (hipOccupancyMaxActiveBlocksPerMultiprocessor(
                    &maxB, (const void*)mega, 256, 0) == hipSuccess && maxB > 0) {
                long g = (long)prop.multiProcessorCount * maxB;
                coopGrid = (int)(g > 1024 ? 1024 : g);
            }
        }
    }

    if (ws_size >= (56ull << 20) && coopGrid >= 256) {
        MegaArgs ma;
        ma.x = x; ma.adj = adj; ma.Ww = Ww; ma.Wb = Wb; ma.A = A;
        ma.wi_u = wi_u; ma.wi_x = wi_x; ma.wf_u = wf_u; ma.wf_x = wf_x;
        ma.wo_u = wo_u; ma.wo_x = wo_x; ma.out = out;
        ma.WwB = WwB; ma.W2T = W2T; ma.wbA = wbA; ma.colsum = rl0;
        ma.maskJ = maskJ; ma.h = h; ma.u = u; ma.hT = hT; ma.att = att;
        void* args[] = {&ma};
        hipLaunchCooperativeKernel((const void*)mega, dim3(coopGrid), dim3(256),
                                   args, 0, stream);
    } else if (ws_size >= (56ull << 20)) {
        k0_w2t<<<64, 256, 0, stream>>>(Ww, Wb, A, WwB, W2T, wbA);
        kmask<<<16384, 256, 0, stream>>>(adj, maskJ);
        k1_hu<<<1024, 256, 0, stream>>>(x, WwB, Wb, W2T, wbA, h, u, hT);
        k2_scores<<<512, 256, 0, stream>>>(h, u, maskJ, att, colpart);
        k2b_recip<<<64, 256, 0, stream>>>(colpart, rl0);
        k3_gemm<<<1024, 256, 0, stream>>>(att, rl0, hT, x,
                                          wi_u, wi_x, wf_u, wf_x, wo_u, wo_x, out);
    } else {
        // minimal-ws fallback: same 6-kernel path with tighter layout
        unsigned short* h2   = (unsigned short*)(ws + (5ull << 20));
        unsigned short* u2   = (unsigned short*)(ws + (9ull << 20));
        unsigned short* hT2  = (unsigned short*)(ws + (13ull << 20));
        unsigned short* att2 = (unsigned short*)(ws + (17ull << 20));
        k0_w2t<<<64, 256, 0, stream>>>(Ww, Wb, A, WwB, W2T, wbA);
        kmask<<<16384, 256, 0, stream>>>(adj, maskJ);
        k1_hu<<<1024, 256, 0, stream>>>(x, WwB, Wb, W2T, wbA, h2, u2, hT2);
        k2_scores<<<512, 256, 0, stream>>>(h2, u2, maskJ, att2, colpart);
        k2b_recip<<<64, 256, 0, stream>>>(colpart, rl0);
        k3_gemm<<<1024, 256, 0, stream>>>(att2, rl0, hT2, x,
                                          wi_u, wi_x, wf_u, wf_x, wo_u, wo_x, out);
    }
}

// Round 11
// 220.924 us; speedup vs baseline: 1.2363x; 1.0122x over previous
//
#include <hip/hip_runtime.h>

// GAT_gate: B=16, N=1024, D=128. FP32 I/O; bf16 MFMA internally, fp32 accum.
//
// Round-11: round-9 6-kernel structure (coop mega removed -- measured neutral
// total, 275us profiled alone; the ~100us gap is a FIXED harness floor, not
// per-dispatch). k2_scores reworked: j-tile pairs, 8 MFMA chains, LDS-staged
// att tile -> fully-covered 64B row writes (fixes the 65MB-vs-34MB write
// amplification seen in r9 counters).
//
//  K0:    WwB = bf16(Ww); W2T = bf16(A^T Ww); wbA = Wb@A (fp32)
//  kmask: adj (64MB fp32) -> 2MB bitmask (standalone wide grid -- r8 lesson)
//  K1:    h = x@Ww^T+Wb ; u = x@W2T^T+wbA -> h,u bf16; hT bf16 [b][d][n]
//  K2s:   grid 512: block = 32 rows i x all j, j in pairs of 16-tiles;
//         att = mask?exp(e):0 bf16 via LDS stage (64B coalesced writes);
//         partial colsums.
//  K2b:   rl0[j] = 1 / sum_iblk colpart
//  K3g:   pure GEMM h' = relu((att*rl0[j]) @ h) vs hT + LSTM-gate epilogue.

#define B_ 16
#define N_ 1024
#define D_ 128

typedef __attribute__((ext_vector_type(8))) short bf16x8;
typedef __attribute__((ext_vector_type(4))) float f32x4;

__device__ __forceinline__ float b2f(unsigned short u) {
    union { unsigned int i; float f; } v; v.i = ((unsigned int)u) << 16; return v.f;
}
__device__ __forceinline__ unsigned short f2b(float f) {
    union { float f; unsigned int i; } v; v.f = f;
    unsigned int x = v.i;
    return (unsigned short)((x + 0x7fffu + ((x >> 16) & 1u)) >> 16);
}
__device__ __forceinline__ float clamp60(float v) {
    return fminf(fmaxf(v, -60.f), 60.f);
}
__device__ __forceinline__ bf16x8 load8f(const float* p) {
    float4 a = *reinterpret_cast<const float4*>(p);
    float4 b = *reinterpret_cast<const float4*>(p + 4);
    bf16x8 v;
    v[0] = (short)f2b(a.x); v[1] = (short)f2b(a.y);
    v[2] = (short)f2b(a.z); v[3] = (short)f2b(a.w);
    v[4] = (short)f2b(b.x); v[5] = (short)f2b(b.y);
    v[6] = (short)f2b(b.z); v[7] = (short)f2b(b.w);
    return v;
}

// ---------------- K0: fold weights ----------------
__global__ __launch_bounds__(256) void k0_w2t(
    const float* __restrict__ Ww, const float* __restrict__ Wb,
    const float* __restrict__ A, unsigned short* __restrict__ WwB,
    unsigned short* __restrict__ W2T, float* __restrict__ wbA) {
    int t = blockIdx.x * 256 + threadIdx.x;
    int l = t >> 7, f = t & 127;
    float acc = 0.f;
    for (int d = 0; d < 128; ++d)
        acc += A[d * 128 + l] * Ww[d * 128 + f];
    W2T[l * 128 + f] = f2b(acc);
    WwB[t] = f2b(Ww[t]);
    if (blockIdx.x == 0 && threadIdx.x < 128) {
        float s = 0.f;
        for (int d = 0; d < 128; ++d) s += Wb[d] * A[d * 128 + threadIdx.x];
        wbA[threadIdx.x] = s;
    }
}

// ---------------- kmask: adj -> bitmask ----------------
__global__ __launch_bounds__(256) void kmask(
    const float* __restrict__ adj, unsigned long long* __restrict__ maskJ) {
    int w = threadIdx.x >> 6, lane = threadIdx.x & 63;
    size_t base = ((size_t)blockIdx.x * 4 + w) * 256;
    unsigned long long w0 = __ballot(adj[base + 0 * 64 + lane] > 0.f);
    unsigned long long w1 = __ballot(adj[base + 1 * 64 + lane] > 0.f);
    unsigned long long w2 = __ballot(adj[base + 2 * 64 + lane] > 0.f);
    unsigned long long w3 = __ballot(adj[base + 3 * 64 + lane] > 0.f);
    unsigned long long o = lane == 0 ? w0 : lane == 1 ? w1 : lane == 2 ? w2 : w3;
    if (lane < 4) maskJ[(base >> 6) + lane] = o;
}

// ---------------- K1: h, u, hT ----------------
__global__ __launch_bounds__(256) void k1_hu(
    const float* __restrict__ x, const unsigned short* __restrict__ WwB,
    const float* __restrict__ Wb, const unsigned short* __restrict__ W2T,
    const float* __restrict__ wbA,
    unsigned short* __restrict__ h, unsigned short* __restrict__ u,
    unsigned short* __restrict__ hT) {
    __shared__ unsigned short lds[16][128];
    int w = threadIdx.x >> 6, lane = threadIdx.x & 63;
    int c = lane & 15, q = lane >> 4;
    int rowbase = blockIdx.x * 16;
    int b = rowbase >> 10;
    int n0 = rowbase & 1023;
    bf16x8 xa[4];
    const float* xrow = x + (size_t)(rowbase + c) * 128;
#pragma unroll
    for (int ks = 0; ks < 4; ++ks)
        xa[ks] = load8f(xrow + ks * 32 + q * 8);
#pragma unroll
    for (int tt = 0; tt < 2; ++tt) {
        int t = w * 2 + tt;
        f32x4 acch = {0.f, 0.f, 0.f, 0.f};
        f32x4 accu = {0.f, 0.f, 0.f, 0.f};
        const unsigned short* wwrow = WwB + (t * 16 + c) * 128;
        const unsigned short* w2row = W2T + (t * 16 + c) * 128;
#pragma unroll
        for (int ks = 0; ks < 4; ++ks) {
            bf16x8 bw = *reinterpret_cast<const bf16x8*>(wwrow + ks * 32 + q * 8);
            bf16x8 b2 = *reinterpret_cast<const bf16x8*>(w2row + ks * 32 + q * 8);
            acch = __builtin_amdgcn_mfma_f32_16x16x32_bf16(xa[ks], bw, acch, 0, 0, 0);
            accu = __builtin_amdgcn_mfma_f32_16x16x32_bf16(xa[ks], b2, accu, 0, 0, 0);
        }
        float wb = Wb[t * 16 + c];
        float ub = wbA[t * 16 + c];
#pragma unroll
        for (int r = 0; r < 4; ++r) {
            int row = rowbase + q * 4 + r;
            unsigned short hv = f2b(acch[r] + wb);
            unsigned short uv = f2b(accu[r] + ub);
            h[(size_t)row * 128 + t * 16 + c] = hv;
            u[(size_t)row * 128 + t * 16 + c] = uv;
            lds[q * 4 + r][t * 16 + c] = hv;
        }
    }
    __syncthreads();
    int tid = threadIdx.x;
    if (tid < 128) {
        int d = tid;
        unsigned int p[8];
#pragma unroll
        for (int k = 0; k < 8; ++k) {
            unsigned int v0 = lds[2 * k][d], v1 = lds[2 * k + 1][d];
            p[k] = v0 | (v1 << 16);
        }
        size_t basehT = ((size_t)(b * 128 + d)) * 1024 + n0;
        uint4* dst = reinterpret_cast<uint4*>(hT + basehT);
        dst[0] = make_uint4(p[0], p[1], p[2], p[3]);
        dst[1] = make_uint4(p[4], p[5], p[6], p[7]);
    }
}

// K2s: grid 512: block = 32 rows i, all 1024 j; j-tile PAIRS; 8 MFMA chains;
// att writes staged in LDS -> 64B fully-covered row segments.
__global__ __launch_bounds__(256) void k2_scores(
    const unsigned short* __restrict__ h, const unsigned short* __restrict__ u,
    const unsigned long long* __restrict__ maskJ,
    unsigned short* __restrict__ att, float* __restrict__ colpart) {
    __shared__ unsigned long long lmask[32][16];
    __shared__ __align__(16) unsigned short stage[4][32][40];  // +8 pad vs 32
    int w = threadIdx.x >> 6, lane = threadIdx.x & 63;
    int c = lane & 15, q = lane >> 4;
    int b = blockIdx.x >> 5;
    int iblk = blockIdx.x & 31;
    int i0 = iblk * 32;
    const unsigned short* hb = h + (size_t)b * N_ * D_;
    const unsigned short* ub = u + (size_t)b * N_ * D_;

    {
        int tid = threadIdx.x;
        lmask[tid >> 4][tid & 15] =
            maskJ[(size_t)(b * 1024 + i0 + (tid >> 4)) * 16 + (tid & 15)];
        lmask[16 + (tid >> 4)][tid & 15] =
            maskJ[(size_t)(b * 1024 + i0 + 16 + (tid >> 4)) * 16 + (tid & 15)];
    }
    __syncthreads();

    bf16x8 Au0[4], Ah0[4], Au1[4], Ah1[4];
#pragma unroll
    for (int ks = 0; ks < 4; ++ks) {
        Au0[ks] = *reinterpret_cast<const bf16x8*>(ub + (i0 + c) * 128 + ks * 32 + q * 8);
        Ah0[ks] = *reinterpret_cast<const bf16x8*>(hb + (i0 + c) * 128 + ks * 32 + q * 8);
        Au1[ks] = *reinterpret_cast<const bf16x8*>(ub + (i0 + 16 + c) * 128 + ks * 32 + q * 8);
        Ah1[ks] = *reinterpret_cast<const bf16x8*>(hb + (i0 + 16 + c) * 128 + ks * 32 + q * 8);
    }
    unsigned short* attrow = att + ((size_t)(b * 1024 + i0)) * 1024;
    float* cprow = colpart + ((size_t)(b * 32 + iblk)) * 1024;

    int jt0 = w * 16;                     // wave w owns tiles jt0..jt0+15
#pragma unroll
    for (int p = 0; p < 8; ++p) {
        int jt = jt0 + p * 2;             // pair (jt, jt+1)
        int j0 = jt * 16;
        bf16x8 Bh[2][4], Bu[2][4];
#pragma unroll
        for (int s = 0; s < 2; ++s)
#pragma unroll
            for (int ks = 0; ks < 4; ++ks) {
                Bh[s][ks] = *reinterpret_cast<const bf16x8*>(
                    hb + (j0 + s * 16 + c) * 128 + ks * 32 + q * 8);
                Bu[s][ks] = *reinterpret_cast<const bf16x8*>(
                    ub + (j0 + s * 16 + c) * 128 + ks * 32 + q * 8);
            }
        f32x4 acc[2][2][2];               // [rowgrp g][jhalf s][prod]
#pragma unroll
        for (int g = 0; g < 2; ++g)
#pragma unroll
            for (int s = 0; s < 2; ++s)
#pragma unroll
                for (int pr = 0; pr < 2; ++pr)
                    acc[g][s][pr] = (f32x4){0.f, 0.f, 0.f, 0.f};
#pragma unroll
        for (int ks = 0; ks < 4; ++ks) {
            acc[0][0][0] = __builtin_amdgcn_mfma_f32_16x16x32_bf16(Au0[ks], Bh[0][ks], acc[0][0][0], 0, 0, 0);
            acc[0][0][1] = __builtin_amdgcn_mfma_f32_16x16x32_bf16(Ah0[ks], Bu[0][ks], acc[0][0][1], 0, 0, 0);
            acc[1][0][0] = __builtin_amdgcn_mfma_f32_16x16x32_bf16(Au1[ks], Bh[0][ks], acc[1][0][0], 0, 0, 0);
            acc[1][0][1] = __builtin_amdgcn_mfma_f32_16x16x32_bf16(Ah1[ks], Bu[0][ks], acc[1][0][1], 0, 0, 0);
            acc[0][1][0] = __builtin_amdgcn_mfma_f32_16x16x32_bf16(Au0[ks], Bh[1][ks], acc[0][1][0], 0, 0, 0);
            acc[0][1][1] = __builtin_amdgcn_mfma_f32_16x16x32_bf16(Ah0[ks], Bu[1][ks], acc[0][1][1], 0, 0, 0);
            acc[1][1][0] = __builtin_amdgcn_mfma_f32_16x16x32_bf16(Au1[ks], Bh[1][ks], acc[1][1][0], 0, 0, 0);
            acc[1][1][1] = __builtin_amdgcn_mfma_f32_16x16x32_bf16(Ah1[ks], Bu[1][ks], acc[1][1][1], 0, 0, 0);
        }
        float colpA = 0.f, colpB = 0.f;
#pragma unroll
        for (int s = 0; s < 2; ++s) {
            int jts = jt + s;
            int wd = jts >> 2, sh = (jts & 3) * 16;
#pragma unroll
            for (int g = 0; g < 2; ++g)
#pragma unroll
                for (int r = 0; r < 4; ++r) {
                    float e = acc[g][s][0][r] + acc[g][s][1][r];
                    int row = g * 16 + q * 4 + r;
                    bool m = (lmask[row][wd] >> (sh + c)) & 1ull;
                    float ex = m ? __expf(clamp60(e)) : 0.f;
                    float cadd = m ? ex : 1.0f;
                    if (s == 0) colpA += cadd; else colpB += cadd;
                    stage[w][row][s * 16 + c] = f2b(ex);
                }
        }
        colpA += __shfl_xor(colpA, 16, 64);
        colpA += __shfl_xor(colpA, 32, 64);
        colpB += __shfl_xor(colpB, 16, 64);
        colpB += __shfl_xor(colpB, 32, 64);
        if (q == 0) {
            cprow[j0 + c] = colpA;
            cprow[j0 + 16 + c] = colpB;
        }
        // write out 32 rows x 64B, fully covered (wave-internal LDS roundtrip)
        int row2 = lane & 31, half = lane >> 5;
        const uint4* sp = reinterpret_cast<const uint4*>(&stage[w][row2][half * 16]);
        uint4 v0 = sp[0], v1 = sp[1];
        uint4* gp = reinterpret_cast<uint4*>(attrow + (size_t)row2 * 1024 + j0 + half * 16);
        gp[0] = v0; gp[1] = v1;
    }
}

// K2b: rl0 = 1/sum(colpart)
__global__ __launch_bounds__(256) void k2b_recip(
    const float* __restrict__ colpart, float* __restrict__ rl0) {
    int g = blockIdx.x * 256 + threadIdx.x;
    int b = g >> 10, j = g & 1023;
    float s = 0.f;
    const float* p = colpart + (size_t)b * 32 * 1024 + j;
    for (int ib = 0; ib < 32; ++ib) s += p[(size_t)ib * 1024];
    rl0[g] = 1.0f / s;
}

// K3g: pure GEMM h' = relu((att*rl0) @ h) + gates. att is bf16.
__global__ __launch_bounds__(256) void k3_gemm(
    const unsigned short* __restrict__ att, const float* __restrict__ rl0,
    const unsigned short* __restrict__ hT, const float* __restrict__ x,
    const float* __restrict__ wi_u, const float* __restrict__ wi_x,
    const float* __restrict__ wf_u, const float* __restrict__ wf_x,
    const float* __restrict__ wo_u, const float* __restrict__ wo_x,
    float* __restrict__ out) {
    __shared__ float red[4][16][129];
    int w = threadIdx.x >> 6, lane = threadIdx.x & 63;
    int c = lane & 15, q = lane >> 4;
    int b = blockIdx.x >> 6;
    int i0 = (blockIdx.x & 63) * 16;
    const unsigned short* attrow = att + ((size_t)(b * 1024 + i0 + c)) * 1024;
    const unsigned short* hTb = hT + (size_t)b * 128 * 1024;
    const float* rl0b = rl0 + b * 1024;
    f32x4 hp[8];
#pragma unroll
    for (int t = 0; t < 8; ++t) hp[t] = (f32x4){0.f, 0.f, 0.f, 0.f};
#pragma unroll
    for (int tt = 0; tt < 8; ++tt) {
        int jp = w * 8 + tt;
        int jb = jp * 32 + q * 8;
        bf16x8 eraw = *reinterpret_cast<const bf16x8*>(attrow + jb);
        float4 r0 = *reinterpret_cast<const float4*>(rl0b + jb);
        float4 r1 = *reinterpret_cast<const float4*>(rl0b + jb + 4);
        bf16x8 av;
        av[0] = (short)f2b(b2f((unsigned short)eraw[0]) * r0.x);
        av[1] = (short)f2b(b2f((unsigned short)eraw[1]) * r0.y);
        av[2] = (short)f2b(b2f((unsigned short)eraw[2]) * r0.z);
        av[3] = (short)f2b(b2f((unsigned short)eraw[3]) * r0.w);
        av[4] = (short)f2b(b2f((unsigned short)eraw[4]) * r1.x);
        av[5] = (short)f2b(b2f((unsigned short)eraw[5]) * r1.y);
        av[6] = (short)f2b(b2f((unsigned short)eraw[6]) * r1.z);
        av[7] = (short)f2b(b2f((unsigned short)eraw[7]) * r1.w);
#pragma unroll
        for (int t = 0; t < 8; ++t) {
            bf16x8 bt = *reinterpret_cast<const bf16x8*>(
                hTb + (size_t)(t * 16 + c) * 1024 + jp * 32 + q * 8);
            hp[t] = __builtin_amdgcn_mfma_f32_16x16x32_bf16(av, bt, hp[t], 0, 0, 0);
        }
    }
#pragma unroll
    for (int t = 0; t < 8; ++t)
#pragma unroll
        for (int r = 0; r < 4; ++r)
            red[w][q * 4 + r][t * 16 + c] = hp[t][r];
    __syncthreads();
    if (w != 0) return;
#pragma unroll
    for (int t = 0; t < 8; ++t)
#pragma unroll
        for (int r = 0; r < 4; ++r)
            hp[t][r] = red[0][q * 4 + r][t * 16 + c] + red[1][q * 4 + r][t * 16 + c]
                     + red[2][q * 4 + r][t * 16 + c] + red[3][q * 4 + r][t * 16 + c];
    float xv[8][4];
#pragma unroll
    for (int t = 0; t < 8; ++t)
#pragma unroll
        for (int r = 0; r < 4; ++r) {
            hp[t][r] = fmaxf(hp[t][r], 0.f);
            xv[t][r] = x[(size_t)(b * 1024 + i0 + q * 4 + r) * 128 + t * 16 + c];
        }
    float wiu[8], wix[8], wfu[8], wfx[8], wou[8], wox[8];
#pragma unroll
    for (int t = 0; t < 8; ++t) {
        wiu[t] = wi_u[t * 16 + c]; wix[t] = wi_x[t * 16 + c];
        wfu[t] = wf_u[t * 16 + c]; wfx[t] = wf_x[t * 16 + c];
        wou[t] = wo_u[t * 16 + c]; wox[t] = wo_x[t * 16 + c];
    }
#pragma unroll
    for (int r = 0; r < 4; ++r) {
        float zi = 0.f, zf = 0.f, zo = 0.f;
#pragma unroll
        for (int t = 0; t < 8; ++t) {
            zi += hp[t][r] * wiu[t] + xv[t][r] * wix[t];
            zf += hp[t][r] * wfu[t] + xv[t][r] * wfx[t];
            zo += hp[t][r] * wou[t] + xv[t][r] * wox[t];
        }
        zi += __shfl_xor(zi, 1, 64); zi += __shfl_xor(zi, 2, 64);
        zi += __shfl_xor(zi, 4, 64); zi += __shfl_xor(zi, 8, 64);
        zf += __shfl_xor(zf, 1, 64); zf += __shfl_xor(zf, 2, 64);
        zf += __shfl_xor(zf, 4, 64); zf += __shfl_xor(zf, 8, 64);
        zo += __shfl_xor(zo, 1, 64); zo += __shfl_xor(zo, 2, 64);
        zo += __shfl_xor(zo, 4, 64); zo += __shfl_xor(zo, 8, 64);
        float ic = 1.f / (1.f + __expf(-zi));
        float fc = 1.f / (1.f + __expf(-zf));
        float oc = 1.f / (1.f + __expf(-zo));
#pragma unroll
        for (int t = 0; t < 8; ++t) {
            float zz = ic * hp[t][r] + fc * xv[t][r];
            float th = 1.f - 2.f / (__expf(2.f * zz) + 1.f);
            out[(size_t)(b * 1024 + i0 + q * 4 + r) * 128 + t * 16 + c] = oc * th;
        }
    }
}

extern "C" void kernel_launch(void* const* d_in, const int* in_sizes, int n_in,
                              void* d_out, int out_size, void* d_ws, size_t ws_size,
                              hipStream_t stream) {
    const float* x    = (const float*)d_in[0];
    const float* adj  = (const float*)d_in[1];
    const float* Ww   = (const float*)d_in[2];
    const float* Wb   = (const float*)d_in[3];
    const float* A    = (const float*)d_in[4];
    const float* wi_u = (const float*)d_in[5];
    const float* wi_x = (const float*)d_in[6];
    const float* wf_u = (const float*)d_in[7];
    const float* wf_x = (const float*)d_in[8];
    const float* wo_u = (const float*)d_in[9];
    const float* wo_x = (const float*)d_in[10];
    float* out = (float*)d_out;
    char* ws = (char*)d_ws;

    if (ws_size >= (56ull << 20)) {
        unsigned short* WwB = (unsigned short*)(ws);                      // 32K
        unsigned short* W2T = (unsigned short*)(ws + (32u << 10));        // 32K
        float* wbA          = (float*)(ws + (64u << 10));                 // 512B
        float* rl0          = (float*)(ws + (128u << 10));                // 64K
        unsigned long long* maskJ = (unsigned long long*)(ws + (256u << 10)); // 2M
        float* colpart      = (float*)(ws + (4ull << 20));                // 2M
        unsigned short* h   = (unsigned short*)(ws + (8ull << 20));       // 4M
        unsigned short* u   = (unsigned short*)(ws + (12ull << 20));      // 4M
        unsigned short* hT  = (unsigned short*)(ws + (16ull << 20));      // 4M
        unsigned short* att = (unsigned short*)(ws + (20ull << 20));      // 32M

        k0_w2t<<<64, 256, 0, stream>>>(Ww, Wb, A, WwB, W2T, wbA);
        kmask<<<16384, 256, 0, stream>>>(adj, maskJ);
        k1_hu<<<1024, 256, 0, stream>>>(x, WwB, Wb, W2T, wbA, h, u, hT);
        k2_scores<<<512, 256, 0, stream>>>(h, u, maskJ, att, colpart);
        k2b_recip<<<64, 256, 0, stream>>>(colpart, rl0);
        k3_gemm<<<1024, 256, 0, stream>>>(att, rl0, hT, x,
                                          wi_u, wi_x, wf_u, wf_x, wo_u, wo_x, out);
    } else {
        // tighter layout (~49MB): same kernels
        unsigned short* WwB = (unsigned short*)(ws);
        unsigned short* W2T = (unsigned short*)(ws + (32u << 10));
        float* wbA          = (float*)(ws + (64u << 10));
        float* rl0          = (float*)(ws + (128u << 10));
        unsigned long long* maskJ = (unsigned long long*)(ws + (256u << 10));
        float* colpart      = (float*)(ws + (3ull << 20));
        unsigned short* h   = (unsigned short*)(ws + (5ull << 20));
        unsigned short* u   = (unsigned short*)(ws + (9ull << 20));
        unsigned short* hT  = (unsigned short*)(ws + (13ull << 20));
        unsigned short* att = (unsigned short*)(ws + (17ull << 20));

        k0_w2t<<<64, 256, 0, stream>>>(Ww, Wb, A, WwB, W2T, wbA);
        kmask<<<16384, 256, 0, stream>>>(adj, maskJ);
        k1_hu<<<1024, 256, 0, stream>>>(x, WwB, Wb, W2T, wbA, h, u, hT);
        k2_scores<<<512, 256, 0, stream>>>(h, u, maskJ, att, colpart);
        k2b_recip<<<64, 256, 0, stream>>>(colpart, rl0);
        k3_gemm<<<1024, 256, 0, stream>>>(att, rl0, hT, x,
                                          wi_u, wi_x, wf_u, wf_x, wo_u, wo_x, out);
    }
}